// Round 7
// baseline (225.034 us; speedup 1.0000x reference)
//
#include <hip/hip_runtime.h>

// ---------------------------------------------------------------------------
// EntropyPrunedSelfAttention  (B=4, N=1024, C=768, H=12, hd=64)
// Round 7: barrier-free register-streaming stats.
//   colP_j = sum_r (e*u_r)*sigma - sum_r e*w_r,  u=1/Z, w=logZ/Z.
//   k_rowz:    Q resident in regs, K streamed, no LDS/barriers -> rowZ atomics
//   k_lsefin:  Z -> lse, (u,w) interleaved pairs
//   k_colstats:K resident in regs, Q+uw streamed, colS/colP in regs -> atomics
//
// Workspace (byte offsets):
//   xb      bf16[4096*768]      @ 0
//   qwb     bf16[2304*768]      @ 6291456
//   pwb     bf16[768*768]       @ 9830400
//   qb      bf16[48*1024*64]    @ 11010048
//   kb      bf16[48*1024*64]    @ 17301504
//   v       f32 [48*1024*64]    @ 23592960
//   ctxb    bf16[4096*768]      @ 36175872
//   lse     f32 [48*1024]       @ 42467328
//   mask    f32 [1024]          @ 42663936
//   keep    int [1]             @ 42668032
//   colSP   f32 [2048]          @ 42668544   (colS[1024] ++ colP[1024])
//   rowZ    f32 [48*1024]       @ 42676736
//   uw      f32 [2*48*1024]     @ 42873344
// total ~43.7 MB (round-1 used 50.5 MB successfully)
// ---------------------------------------------------------------------------

typedef __bf16 bf16x8 __attribute__((ext_vector_type(8)));
typedef __bf16 bf16x4 __attribute__((ext_vector_type(4)));
typedef float  f32x4  __attribute__((ext_vector_type(4)));

#define MFMA16(a, b, c) __builtin_amdgcn_mfma_f32_16x16x32_bf16((a), (b), (c), 0, 0, 0)
#define LOG2E_8 0.18033688f  /* 0.125 * log2(e) */

// --- 1. fp32 -> bf16 conversion + zero colSP/rowZ/keepCnt ------------------
__global__ __launch_bounds__(256) void kc_conv(
    const float* __restrict__ x, const float* __restrict__ qw, const float* __restrict__ pw,
    __bf16* __restrict__ xb, __bf16* __restrict__ qwb, __bf16* __restrict__ pwb,
    float* __restrict__ colSP, float* __restrict__ rowZ, int* __restrict__ keepCnt)
{
  const int i = blockIdx.x * 256 + threadIdx.x;
  const float4* src;
  __bf16* dst;
  int j;
  if (i < 786432)       { src = (const float4*)x;  dst = xb;  j = i; }
  else if (i < 1228800) { src = (const float4*)qw; dst = qwb; j = i - 786432; }
  else                  { src = (const float4*)pw; dst = pwb; j = i - 1228800; }
  const float4 f = src[j];
  bf16x4 o;
  o[0] = (__bf16)f.x; o[1] = (__bf16)f.y; o[2] = (__bf16)f.z; o[3] = (__bf16)f.w;
  *(bf16x4*)(dst + 4 * (size_t)j) = o;
  if (i < 2048) colSP[i] = 0.f;
  if (i < 49152) rowZ[i] = 0.f;
  if (i == 0) *keepCnt = 0;
}

// --- 2. QKV GEMM (software-pipelined): qkv = xb @ qwb.T --------------------
__global__ __launch_bounds__(256) void kg_qkv(
    const __bf16* __restrict__ A, const __bf16* __restrict__ Bm,
    __bf16* __restrict__ qb, __bf16* __restrict__ kb, float* __restrict__ v)
{
  __shared__ __bf16 As[64 * 72];
  __shared__ __bf16 Bs[64 * 72];
  const int tid = threadIdx.x;
  const int w = tid >> 6, lane = tid & 63, quad = lane >> 4, l = lane & 15;
  const int r0 = blockIdx.y * 64, c0 = blockIdx.x * 64;
  const int row = tid >> 3, ko = (tid & 7) * 8;
  const f32x4 zero = {0.f, 0.f, 0.f, 0.f};
  f32x4 acc[4];
#pragma unroll
  for (int ct = 0; ct < 4; ++ct) acc[ct] = zero;

  uint4 a0 = *(const uint4*)(A + (size_t)(r0 + row) * 768 + ko);
  uint4 a1 = *(const uint4*)(A + (size_t)(r0 + row + 32) * 768 + ko);
  uint4 b0 = *(const uint4*)(Bm + (size_t)(c0 + row) * 768 + ko);
  uint4 b1 = *(const uint4*)(Bm + (size_t)(c0 + row + 32) * 768 + ko);

  for (int k0 = 0; k0 < 768; k0 += 64) {
    __syncthreads();
    *(uint4*)&As[row * 72 + ko] = a0;
    *(uint4*)&As[(row + 32) * 72 + ko] = a1;
    *(uint4*)&Bs[row * 72 + ko] = b0;
    *(uint4*)&Bs[(row + 32) * 72 + ko] = b1;
    __syncthreads();
    if (k0 < 704) {
      a0 = *(const uint4*)(A + (size_t)(r0 + row) * 768 + k0 + 64 + ko);
      a1 = *(const uint4*)(A + (size_t)(r0 + row + 32) * 768 + k0 + 64 + ko);
      b0 = *(const uint4*)(Bm + (size_t)(c0 + row) * 768 + k0 + 64 + ko);
      b1 = *(const uint4*)(Bm + (size_t)(c0 + row + 32) * 768 + k0 + 64 + ko);
    }
    const bf16x8 af0 = *(const bf16x8*)&As[(w * 16 + l) * 72 + quad * 8];
    const bf16x8 af1 = *(const bf16x8*)&As[(w * 16 + l) * 72 + 32 + quad * 8];
#pragma unroll
    for (int ct = 0; ct < 4; ++ct) {
      const bf16x8 bf0 = *(const bf16x8*)&Bs[(ct * 16 + l) * 72 + quad * 8];
      const bf16x8 bf1 = *(const bf16x8*)&Bs[(ct * 16 + l) * 72 + 32 + quad * 8];
      acc[ct] = MFMA16(af0, bf0, acc[ct]);
      acc[ct] = MFMA16(af1, bf1, acc[ct]);
    }
  }
  const int part = c0 / 768;
  const int h = (c0 % 768) >> 6;
#pragma unroll
  for (int ct = 0; ct < 4; ++ct) {
    const int d = ct * 16 + l;
#pragma unroll
    for (int i = 0; i < 4; ++i) {
      const int rg = r0 + w * 16 + quad * 4 + i;
      const int b_ = rg >> 10, n = rg & 1023;
      const size_t off = ((size_t)(b_ * 12 + h) * 1024 + n) * 64 + d;
      const float val = acc[ct][i];
      if (part == 0)      qb[off] = (__bf16)val;
      else if (part == 1) kb[off] = (__bf16)val;
      else                v[off]  = val;
    }
  }
}

// --- 3a. rowZ: barrier-free streaming. grid (48, 16, 2) --------------------
// Block = (bh, 64 rows, col-half). Wave owns 16 rows (Q resident in regs),
// streams 32 K column-tiles of 16 straight from global into MFMA operands.
__global__ __launch_bounds__(256) void k_rowz(
    const __bf16* __restrict__ qb, const __bf16* __restrict__ kb,
    float* __restrict__ rowZ)
{
  const int tid = threadIdx.x;
  const int w = tid >> 6, lane = tid & 63, quad = lane >> 4, l = lane & 15;
  const int bh = blockIdx.x, r0 = blockIdx.y * 64, cbase = blockIdx.z * 512;
  const __bf16* qrow = qb + ((size_t)bh * 1024 + r0 + w * 16 + l) * 64;
  const bf16x8 aq0 = *(const bf16x8*)(qrow + quad * 8);
  const bf16x8 aq1 = *(const bf16x8*)(qrow + 32 + quad * 8);
  const __bf16* kbase = kb + ((size_t)bh * 1024 + cbase + l) * 64 + quad * 8;
  const f32x4 zero = {0.f, 0.f, 0.f, 0.f};
  float z[4] = {0.f, 0.f, 0.f, 0.f};
#pragma unroll 8
  for (int chunk = 0; chunk < 32; ++chunk) {
    const __bf16* kp = kbase + (size_t)chunk * 16 * 64;
    const bf16x8 kf0 = *(const bf16x8*)kp;
    const bf16x8 kf1 = *(const bf16x8*)(kp + 32);
    f32x4 acc = MFMA16(aq0, kf0, zero);
    acc = MFMA16(aq1, kf1, acc);
#pragma unroll
    for (int r = 0; r < 4; ++r) z[r] += exp2f(acc[r] * LOG2E_8);
  }
#pragma unroll
  for (int off = 1; off < 16; off <<= 1) {
#pragma unroll
    for (int r = 0; r < 4; ++r) z[r] += __shfl_xor(z[r], off);
  }
  if (l == 0) {
#pragma unroll
    for (int r = 0; r < 4; ++r)
      atomicAdd(&rowZ[bh * 1024 + r0 + w * 16 + quad * 4 + r], z[r]);
  }
}

// --- 3b. finalize: lse = log Z, uw = (1/Z, logZ/Z) interleaved -------------
__global__ void k_lsefin(const float* __restrict__ rowZ, float* __restrict__ lse,
                         float* __restrict__ uw)
{
  const int i = blockIdx.x * 256 + threadIdx.x;
  const float Z = rowZ[i];
  const float lg = __logf(Z);
  const float u = 1.0f / Z;
  lse[i] = lg;
  float2 p; p.x = u; p.y = lg * u;
  *(float2*)(uw + 2 * (size_t)i) = p;
}

// --- 3c. colstats: barrier-free streaming. grid (48, 16, 2) ----------------
// Block = (bh, 64 cols, row-half). Wave owns 16 cols (K resident in regs),
// streams 32 Q row-tiles + uw pairs; colS/colP accumulate in registers.
__global__ __launch_bounds__(256) void k_colstats(
    const __bf16* __restrict__ qb, const __bf16* __restrict__ kb,
    const float* __restrict__ uw, float* __restrict__ colSP)
{
  const int tid = threadIdx.x;
  const int w = tid >> 6, lane = tid & 63, quad = lane >> 4, l = lane & 15;
  const int bh = blockIdx.x, c0 = blockIdx.y * 64, mbase = blockIdx.z * 512;
  const __bf16* krow = kb + ((size_t)bh * 1024 + c0 + w * 16 + l) * 64;
  const bf16x8 kf0 = *(const bf16x8*)(krow + quad * 8);
  const bf16x8 kf1 = *(const bf16x8*)(krow + 32 + quad * 8);
  const __bf16* qbase = qb + ((size_t)bh * 1024 + mbase + l) * 64 + quad * 8;
  const float* uwbase = uw + 2 * ((size_t)bh * 1024 + mbase + quad * 4);
  const f32x4 zero = {0.f, 0.f, 0.f, 0.f};
  float cs = 0.f, cp = 0.f;
#pragma unroll 8
  for (int chunk = 0; chunk < 32; ++chunk) {
    const __bf16* qp = qbase + (size_t)chunk * 16 * 64;
    const bf16x8 aq0 = *(const bf16x8*)qp;
    const bf16x8 aq1 = *(const bf16x8*)(qp + 32);
    const float4 uw0 = *(const float4*)(uwbase + chunk * 32);
    const float4 uw1 = *(const float4*)(uwbase + chunk * 32 + 4);
    f32x4 acc = MFMA16(aq0, kf0, zero);
    acc = MFMA16(aq1, kf1, acc);
    const float uu[4] = {uw0.x, uw0.z, uw1.x, uw1.z};
    const float ww[4] = {uw0.y, uw0.w, uw1.y, uw1.w};
#pragma unroll
    for (int r = 0; r < 4; ++r) {
      const float sg = acc[r] * 0.125f;
      const float e = exp2f(acc[r] * LOG2E_8);
      const float t = e * uu[r];
      cs += t;
      cp += t * sg - e * ww[r];
    }
  }
  cs += __shfl_xor(cs, 16); cs += __shfl_xor(cs, 32);
  cp += __shfl_xor(cp, 16); cp += __shfl_xor(cp, 32);
  if (lane < 16) {
    atomicAdd(&colSP[c0 + w * 16 + l], cs);
    atomicAdd(&colSP[1024 + c0 + w * 16 + l], cp);
  }
}

// --- 4. entropy -> mask + keepCnt ------------------------------------------
__global__ void k_mask(const float* __restrict__ colSP, const int* __restrict__ cur_epoch,
                       float* __restrict__ mask, int* __restrict__ keepCnt)
{
  const int j = threadIdx.x;
  const float s = colSP[j];
  const float ent = __logf(s) - colSP[1024 + j] / s;
  const int ce = cur_epoch[0];
  float factor = 0.f;
  for (int i = 1; i <= ce; ++i) factor += __expf(-(float)i);
  factor *= 5.0f;
  const float thr = __logf(768.0f) - factor;
  const int keep = (ent <= thr) ? 1 : 0;
  mask[j] = keep ? 1.0f : 0.0f;
  if (keep) atomicAdd(keepCnt, 1);
}

// --- 5. masked AV -> ctxb (bf16). No-op when no column survives. -----------
__global__ __launch_bounds__(256) void k_av(
    const __bf16* __restrict__ qb, const __bf16* __restrict__ kb,
    const float* __restrict__ v, const float* __restrict__ lse,
    const float* __restrict__ mask, const int* __restrict__ keepCnt,
    __bf16* __restrict__ ctxb)
{
  if (*keepCnt == 0) return;  // ctxb unused downstream in this case
  const int tid = threadIdx.x;
  const int bh = blockIdx.x, r0 = blockIdx.y * 32;
  const int b_ = bh / 12, h = bh % 12;
  __shared__ float qs[32][64];
  __shared__ float pbuf[4][8][64];
  for (int i = tid; i < 2048; i += 256)
    qs[i >> 6][i & 63] = (float)qb[((size_t)bh * 1024 + r0) * 64 + i];
  __syncthreads();
  const int w = tid >> 6, l = tid & 63, rb = w * 8;
  float ls[8];
#pragma unroll
  for (int i = 0; i < 8; ++i) ls[i] = lse[bh * 1024 + r0 + rb + i];
  float acc[8] = {};
  for (int chunk = 0; chunk < 16; ++chunk) {
    const float mk = mask[chunk * 64 + l];
    if (__ballot(mk != 0.0f) == 0ull) continue;  // block-uniform
    const __bf16* kp = kb + ((size_t)bh * 1024 + chunk * 64 + l) * 64;
    float s[8] = {};
    for (int d0 = 0; d0 < 64; d0 += 8) {
      const bf16x8 kf = *(const bf16x8*)(kp + d0);
#pragma unroll
      for (int dd = 0; dd < 8; ++dd) {
        const float kv = (float)kf[dd];
#pragma unroll
        for (int i = 0; i < 8; ++i) s[i] += qs[rb + i][d0 + dd] * kv;
      }
    }
    __syncthreads();
#pragma unroll
    for (int i = 0; i < 8; ++i)
      pbuf[w][i][l] = __expf(s[i] * 0.125f - ls[i]) * mk;
    __syncthreads();
    const float* vp = v + ((size_t)bh * 1024 + chunk * 64) * 64 + l;
    for (int jj = 0; jj < 64; ++jj) {
      const float vv = vp[(size_t)jj * 64];
#pragma unroll
      for (int i = 0; i < 8; ++i) acc[i] += pbuf[w][i][jj] * vv;
    }
  }
#pragma unroll
  for (int i = 0; i < 8; ++i)
    ctxb[((size_t)(b_ * 1024 + r0 + rb + i)) * 768 + h * 64 + l] = (__bf16)acc[i];
}

// --- 6. proj GEMM: out = ctxb @ pwb.T + bias; bias-only when keep==0 -------
__global__ __launch_bounds__(256) void kg_proj(
    const __bf16* __restrict__ A, const __bf16* __restrict__ Bm,
    const float* __restrict__ bias, const int* __restrict__ keepCnt,
    float* __restrict__ out)
{
  const int tid = threadIdx.x;
  const int w = tid >> 6, lane = tid & 63, quad = lane >> 4, l = lane & 15;
  const int r0 = blockIdx.y * 64, c0 = blockIdx.x * 64;
  if (*keepCnt == 0) {  // ctx == 0 -> out = bias (uniform branch)
#pragma unroll
    for (int ct = 0; ct < 4; ++ct) {
      const int c = c0 + ct * 16 + l;
      const float bv = bias[c];
#pragma unroll
      for (int i = 0; i < 4; ++i) {
        const int rg = r0 + w * 16 + quad * 4 + i;
        out[(size_t)rg * 768 + c] = bv;
      }
    }
    return;
  }
  __shared__ __bf16 As[64 * 72];
  __shared__ __bf16 Bs[64 * 72];
  const int row = tid >> 3, ko = (tid & 7) * 8;
  const f32x4 zero = {0.f, 0.f, 0.f, 0.f};
  f32x4 acc[4];
#pragma unroll
  for (int ct = 0; ct < 4; ++ct) acc[ct] = zero;

  uint4 a0 = *(const uint4*)(A + (size_t)(r0 + row) * 768 + ko);
  uint4 a1 = *(const uint4*)(A + (size_t)(r0 + row + 32) * 768 + ko);
  uint4 b0 = *(const uint4*)(Bm + (size_t)(c0 + row) * 768 + ko);
  uint4 b1 = *(const uint4*)(Bm + (size_t)(c0 + row + 32) * 768 + ko);

  for (int k0 = 0; k0 < 768; k0 += 64) {
    __syncthreads();
    *(uint4*)&As[row * 72 + ko] = a0;
    *(uint4*)&As[(row + 32) * 72 + ko] = a1;
    *(uint4*)&Bs[row * 72 + ko] = b0;
    *(uint4*)&Bs[(row + 32) * 72 + ko] = b1;
    __syncthreads();
    if (k0 < 704) {
      a0 = *(const uint4*)(A + (size_t)(r0 + row) * 768 + k0 + 64 + ko);
      a1 = *(const uint4*)(A + (size_t)(r0 + row + 32) * 768 + k0 + 64 + ko);
      b0 = *(const uint4*)(Bm + (size_t)(c0 + row) * 768 + k0 + 64 + ko);
      b1 = *(const uint4*)(Bm + (size_t)(c0 + row + 32) * 768 + k0 + 64 + ko);
    }
    const bf16x8 af0 = *(const bf16x8*)&As[(w * 16 + l) * 72 + quad * 8];
    const bf16x8 af1 = *(const bf16x8*)&As[(w * 16 + l) * 72 + 32 + quad * 8];
#pragma unroll
    for (int ct = 0; ct < 4; ++ct) {
      const bf16x8 bf0 = *(const bf16x8*)&Bs[(ct * 16 + l) * 72 + quad * 8];
      const bf16x8 bf1 = *(const bf16x8*)&Bs[(ct * 16 + l) * 72 + 32 + quad * 8];
      acc[ct] = MFMA16(af0, bf0, acc[ct]);
      acc[ct] = MFMA16(af1, bf1, acc[ct]);
    }
  }
#pragma unroll
  for (int ct = 0; ct < 4; ++ct) {
    const int c = c0 + ct * 16 + l;
#pragma unroll
    for (int i = 0; i < 4; ++i) {
      const int rg = r0 + w * 16 + quad * 4 + i;
      out[(size_t)rg * 768 + c] = acc[ct][i] + bias[c];
    }
  }
}

extern "C" void kernel_launch(void* const* d_in, const int* in_sizes, int n_in,
                              void* d_out, int out_size, void* d_ws, size_t ws_size,
                              hipStream_t stream)
{
  const float* x      = (const float*)d_in[0];
  const float* qkv_w  = (const float*)d_in[1];
  const float* proj_w = (const float*)d_in[2];
  const float* proj_b = (const float*)d_in[3];
  const int*   cur_ep = (const int*)d_in[4];

  char* W = (char*)d_ws;
  __bf16* xb    = (__bf16*)(W + 0);
  __bf16* qwb   = (__bf16*)(W + 6291456);
  __bf16* pwb   = (__bf16*)(W + 9830400);
  __bf16* qb    = (__bf16*)(W + 11010048);
  __bf16* kb    = (__bf16*)(W + 17301504);
  float*  v     = (float*) (W + 23592960);
  __bf16* ctxb  = (__bf16*)(W + 36175872);
  float*  lse   = (float*) (W + 42467328);
  float*  mask  = (float*) (W + 42663936);
  int*    keep  = (int*)   (W + 42668032);
  float*  colSP = (float*) (W + 42668544);
  float*  rowZ  = (float*) (W + 42676736);
  float*  uw    = (float*) (W + 42873344);
  float*  out   = (float*)d_out;

  kc_conv<<<5376, 256, 0, stream>>>(x, qkv_w, proj_w, xb, qwb, pwb, colSP, rowZ, keep);
  kg_qkv<<<dim3(36, 64), 256, 0, stream>>>(xb, qwb, qb, kb, v);
  k_rowz<<<dim3(48, 16, 2), 256, 0, stream>>>(qb, kb, rowZ);
  k_lsefin<<<192, 256, 0, stream>>>(rowZ, lse, uw);
  k_colstats<<<dim3(48, 16, 2), 256, 0, stream>>>(qb, kb, uw, colSP);
  k_mask<<<1, 1024, 0, stream>>>(colSP, cur_ep, mask, keep);
  k_av<<<dim3(48, 32), 256, 0, stream>>>(qb, kb, v, lse, mask, keep, ctxb);
  kg_proj<<<dim3(12, 64), 256, 0, stream>>>(ctxb, pwb, proj_b, keep, out);
}

// Round 8
// 213.638 us; speedup vs baseline: 1.0533x; 1.0533x over previous
//
#include <hip/hip_runtime.h>

// ---------------------------------------------------------------------------
// EntropyPrunedSelfAttention  (B=4, N=1024, C=768, H=12, hd=64)
// Round 8: big-stage fused stats. Ks staged 256 rows/iteration (8 outstanding
// 16B loads/thread, 8 barriers total vs 64), both passes in one kernel,
// u/w computed in registers (no lsefin/rowZ/uw). 6 launches total.
//
// Workspace (byte offsets):
//   xb      bf16[4096*768]      @ 0
//   qwb     bf16[2304*768]      @ 6291456
//   pwb     bf16[768*768]       @ 9830400
//   qb      bf16[48*1024*64]    @ 11010048
//   kb      bf16[48*1024*64]    @ 17301504
//   v       f32 [48*1024*64]    @ 23592960
//   ctxb    bf16[4096*768]      @ 36175872
//   lse     f32 [48*1024]       @ 42467328
//   mask    f32 [1024]          @ 42663936
//   keep    int [1]             @ 42668032
//   colSP   f32 [2048]          @ 42668544   (colS[1024] ++ colP[1024])
// total ~42.7 MB
// ---------------------------------------------------------------------------

typedef __bf16 bf16x8 __attribute__((ext_vector_type(8)));
typedef __bf16 bf16x4 __attribute__((ext_vector_type(4)));
typedef float  f32x4  __attribute__((ext_vector_type(4)));

#define MFMA16(a, b, c) __builtin_amdgcn_mfma_f32_16x16x32_bf16((a), (b), (c), 0, 0, 0)
#define LOG2E_8 0.18033688f  /* 0.125 * log2(e) */

// --- 1. fp32 -> bf16 conversion + zero colSP/keepCnt -----------------------
__global__ __launch_bounds__(256) void kc_conv(
    const float* __restrict__ x, const float* __restrict__ qw, const float* __restrict__ pw,
    __bf16* __restrict__ xb, __bf16* __restrict__ qwb, __bf16* __restrict__ pwb,
    float* __restrict__ colSP, int* __restrict__ keepCnt)
{
  const int i = blockIdx.x * 256 + threadIdx.x;
  const float4* src;
  __bf16* dst;
  int j;
  if (i < 786432)       { src = (const float4*)x;  dst = xb;  j = i; }
  else if (i < 1228800) { src = (const float4*)qw; dst = qwb; j = i - 786432; }
  else                  { src = (const float4*)pw; dst = pwb; j = i - 1228800; }
  const float4 f = src[j];
  bf16x4 o;
  o[0] = (__bf16)f.x; o[1] = (__bf16)f.y; o[2] = (__bf16)f.z; o[3] = (__bf16)f.w;
  *(bf16x4*)(dst + 4 * (size_t)j) = o;
  if (i < 2048) colSP[i] = 0.f;
  if (i == 0) *keepCnt = 0;
}

// --- 2. QKV GEMM (software-pipelined): qkv = xb @ qwb.T --------------------
__global__ __launch_bounds__(256) void kg_qkv(
    const __bf16* __restrict__ A, const __bf16* __restrict__ Bm,
    __bf16* __restrict__ qb, __bf16* __restrict__ kb, float* __restrict__ v)
{
  __shared__ __bf16 As[64 * 72];
  __shared__ __bf16 Bs[64 * 72];
  const int tid = threadIdx.x;
  const int w = tid >> 6, lane = tid & 63, quad = lane >> 4, l = lane & 15;
  const int r0 = blockIdx.y * 64, c0 = blockIdx.x * 64;
  const int row = tid >> 3, ko = (tid & 7) * 8;
  const f32x4 zero = {0.f, 0.f, 0.f, 0.f};
  f32x4 acc[4];
#pragma unroll
  for (int ct = 0; ct < 4; ++ct) acc[ct] = zero;

  uint4 a0 = *(const uint4*)(A + (size_t)(r0 + row) * 768 + ko);
  uint4 a1 = *(const uint4*)(A + (size_t)(r0 + row + 32) * 768 + ko);
  uint4 b0 = *(const uint4*)(Bm + (size_t)(c0 + row) * 768 + ko);
  uint4 b1 = *(const uint4*)(Bm + (size_t)(c0 + row + 32) * 768 + ko);

  for (int k0 = 0; k0 < 768; k0 += 64) {
    __syncthreads();
    *(uint4*)&As[row * 72 + ko] = a0;
    *(uint4*)&As[(row + 32) * 72 + ko] = a1;
    *(uint4*)&Bs[row * 72 + ko] = b0;
    *(uint4*)&Bs[(row + 32) * 72 + ko] = b1;
    __syncthreads();
    if (k0 < 704) {
      a0 = *(const uint4*)(A + (size_t)(r0 + row) * 768 + k0 + 64 + ko);
      a1 = *(const uint4*)(A + (size_t)(r0 + row + 32) * 768 + k0 + 64 + ko);
      b0 = *(const uint4*)(Bm + (size_t)(c0 + row) * 768 + k0 + 64 + ko);
      b1 = *(const uint4*)(Bm + (size_t)(c0 + row + 32) * 768 + k0 + 64 + ko);
    }
    const bf16x8 af0 = *(const bf16x8*)&As[(w * 16 + l) * 72 + quad * 8];
    const bf16x8 af1 = *(const bf16x8*)&As[(w * 16 + l) * 72 + 32 + quad * 8];
#pragma unroll
    for (int ct = 0; ct < 4; ++ct) {
      const bf16x8 bf0 = *(const bf16x8*)&Bs[(ct * 16 + l) * 72 + quad * 8];
      const bf16x8 bf1 = *(const bf16x8*)&Bs[(ct * 16 + l) * 72 + 32 + quad * 8];
      acc[ct] = MFMA16(af0, bf0, acc[ct]);
      acc[ct] = MFMA16(af1, bf1, acc[ct]);
    }
  }
  const int part = c0 / 768;
  const int h = (c0 % 768) >> 6;
#pragma unroll
  for (int ct = 0; ct < 4; ++ct) {
    const int d = ct * 16 + l;
#pragma unroll
    for (int i = 0; i < 4; ++i) {
      const int rg = r0 + w * 16 + quad * 4 + i;
      const int b_ = rg >> 10, n = rg & 1023;
      const size_t off = ((size_t)(b_ * 12 + h) * 1024 + n) * 64 + d;
      const float val = acc[ct][i];
      if (part == 0)      qb[off] = (__bf16)val;
      else if (part == 1) kb[off] = (__bf16)val;
      else                v[off]  = val;
    }
  }
}

// --- 3. fused stats, big stages --------------------------------------------
// grid (48, 16): block = (bh, 64 rows). Wave w owns rows w*16..w*16+15 and
// covers all 1024 cols -> Z wave-complete after pass 1; u,w in registers.
// Staging: 256 K-rows per stage (Ks[256][72], 8x uint4/thread, prefetched).
__global__ __launch_bounds__(256) void ks_fused(
    const __bf16* __restrict__ qb, const __bf16* __restrict__ kb,
    float* __restrict__ lse, float* __restrict__ colSP)
{
  __shared__ __bf16 Ks[256 * 72];
  __shared__ float sS[1024];
  __shared__ float sP[1024];
  const int tid = threadIdx.x;
  const int w = tid >> 6, lane = tid & 63, quad = lane >> 4, l = lane & 15;
  const int bh = blockIdx.x, r0 = blockIdx.y * 64;
  for (int i = tid; i < 1024; i += 256) { sS[i] = 0.f; sP[i] = 0.f; }

  const __bf16* qrow = qb + ((size_t)bh * 1024 + r0 + w * 16 + l) * 64;
  const bf16x8 aq0 = *(const bf16x8*)(qrow + quad * 8);
  const bf16x8 aq1 = *(const bf16x8*)(qrow + 32 + quad * 8);
  const uint4* kb4 = (const uint4*)(kb + (size_t)bh * 65536);  // [1024][64] -> 8192 uint4
  const f32x4 zero = {0.f, 0.f, 0.f, 0.f};

  // prefetch stage 0 (8 outstanding 16B loads)
  uint4 kreg[8];
#pragma unroll
  for (int i = 0; i < 8; ++i) kreg[i] = kb4[i * 256 + tid];

  float z[4] = {0.f, 0.f, 0.f, 0.f};
  // ---- pass 1: row sums of exp ----
  for (int stage = 0; stage < 4; ++stage) {
    __syncthreads();  // previous compute done -> LDS writable
#pragma unroll
    for (int i = 0; i < 8; ++i) {
      const int g = i * 256 + tid;
      *(uint4*)&Ks[(g >> 3) * 72 + (g & 7) * 8] = kreg[i];
    }
    __syncthreads();  // staging visible
    const int nxt = (stage < 3) ? (stage + 1) : 0;  // stage 3 prefetches pass-2 stage 0
#pragma unroll
    for (int i = 0; i < 8; ++i) kreg[i] = kb4[nxt * 2048 + i * 256 + tid];
#pragma unroll
    for (int ct = 0; ct < 16; ++ct) {
      const bf16x8 kf0 = *(const bf16x8*)&Ks[(ct * 16 + l) * 72 + quad * 8];
      const bf16x8 kf1 = *(const bf16x8*)&Ks[(ct * 16 + l) * 72 + 32 + quad * 8];
      f32x4 acc = MFMA16(aq0, kf0, zero);
      acc = MFMA16(aq1, kf1, acc);
#pragma unroll
      for (int r = 0; r < 4; ++r) z[r] += exp2f(acc[r] * LOG2E_8);
    }
  }
#pragma unroll
  for (int off = 1; off < 16; off <<= 1) {
#pragma unroll
    for (int r = 0; r < 4; ++r) z[r] += __shfl_xor(z[r], off);
  }
  float uu[4], ww[4];
#pragma unroll
  for (int r = 0; r < 4; ++r) {
    const float lg = __logf(z[r]);
    uu[r] = 1.0f / z[r];
    ww[r] = lg * uu[r];
    if (l == 0) lse[bh * 1024 + r0 + w * 16 + quad * 4 + r] = lg;
  }

  // ---- pass 2: column sums of p and p*logp ----
  for (int stage = 0; stage < 4; ++stage) {
    __syncthreads();
#pragma unroll
    for (int i = 0; i < 8; ++i) {
      const int g = i * 256 + tid;
      *(uint4*)&Ks[(g >> 3) * 72 + (g & 7) * 8] = kreg[i];
    }
    __syncthreads();
    if (stage < 3) {
#pragma unroll
      for (int i = 0; i < 8; ++i) kreg[i] = kb4[(stage + 1) * 2048 + i * 256 + tid];
    }
#pragma unroll
    for (int ct = 0; ct < 16; ++ct) {
      const bf16x8 kf0 = *(const bf16x8*)&Ks[(ct * 16 + l) * 72 + quad * 8];
      const bf16x8 kf1 = *(const bf16x8*)&Ks[(ct * 16 + l) * 72 + 32 + quad * 8];
      f32x4 acc = MFMA16(aq0, kf0, zero);
      acc = MFMA16(aq1, kf1, acc);
      float cs = 0.f, cp = 0.f;
#pragma unroll
      for (int r = 0; r < 4; ++r) {
        const float sg = acc[r] * 0.125f;
        const float e = exp2f(acc[r] * LOG2E_8);
        const float t = e * uu[r];
        cs += t;
        cp += t * sg - e * ww[r];
      }
      cs += __shfl_xor(cs, 16); cs += __shfl_xor(cs, 32);
      cp += __shfl_xor(cp, 16); cp += __shfl_xor(cp, 32);
      if (lane < 16) {
        atomicAdd(&sS[stage * 256 + ct * 16 + l], cs);  // 4-way (waves), LDS
        atomicAdd(&sP[stage * 256 + ct * 16 + l], cp);
      }
    }
  }
  __syncthreads();
  for (int i = tid; i < 1024; i += 256) {
    atomicAdd(&colSP[i], sS[i]);          // 16 row-blocks per address
    atomicAdd(&colSP[1024 + i], sP[i]);
  }
}

// --- 4. entropy -> mask + keepCnt ------------------------------------------
__global__ void k_mask(const float* __restrict__ colSP, const int* __restrict__ cur_epoch,
                       float* __restrict__ mask, int* __restrict__ keepCnt)
{
  const int j = threadIdx.x;
  const float s = colSP[j];
  const float ent = __logf(s) - colSP[1024 + j] / s;
  const int ce = cur_epoch[0];
  float factor = 0.f;
  for (int i = 1; i <= ce; ++i) factor += __expf(-(float)i);
  factor *= 5.0f;
  const float thr = __logf(768.0f) - factor;
  const int keep = (ent <= thr) ? 1 : 0;
  mask[j] = keep ? 1.0f : 0.0f;
  if (keep) atomicAdd(keepCnt, 1);
}

// --- 5. masked AV -> ctxb (bf16). No-op when no column survives. -----------
__global__ __launch_bounds__(256) void k_av(
    const __bf16* __restrict__ qb, const __bf16* __restrict__ kb,
    const float* __restrict__ v, const float* __restrict__ lse,
    const float* __restrict__ mask, const int* __restrict__ keepCnt,
    __bf16* __restrict__ ctxb)
{
  if (*keepCnt == 0) return;  // ctxb unused downstream in this case
  const int tid = threadIdx.x;
  const int bh = blockIdx.x, r0 = blockIdx.y * 32;
  const int b_ = bh / 12, h = bh % 12;
  __shared__ float qs[32][64];
  __shared__ float pbuf[4][8][64];
  for (int i = tid; i < 2048; i += 256)
    qs[i >> 6][i & 63] = (float)qb[((size_t)bh * 1024 + r0) * 64 + i];
  __syncthreads();
  const int w = tid >> 6, l = tid & 63, rb = w * 8;
  float ls[8];
#pragma unroll
  for (int i = 0; i < 8; ++i) ls[i] = lse[bh * 1024 + r0 + rb + i];
  float acc[8] = {};
  for (int chunk = 0; chunk < 16; ++chunk) {
    const float mk = mask[chunk * 64 + l];
    if (__ballot(mk != 0.0f) == 0ull) continue;  // block-uniform
    const __bf16* kp = kb + ((size_t)bh * 1024 + chunk * 64 + l) * 64;
    float s[8] = {};
    for (int d0 = 0; d0 < 64; d0 += 8) {
      const bf16x8 kf = *(const bf16x8*)(kp + d0);
#pragma unroll
      for (int dd = 0; dd < 8; ++dd) {
        const float kv = (float)kf[dd];
#pragma unroll
        for (int i = 0; i < 8; ++i) s[i] += qs[rb + i][d0 + dd] * kv;
      }
    }
    __syncthreads();
#pragma unroll
    for (int i = 0; i < 8; ++i)
      pbuf[w][i][l] = __expf(s[i] * 0.125f - ls[i]) * mk;
    __syncthreads();
    const float* vp = v + ((size_t)bh * 1024 + chunk * 64) * 64 + l;
    for (int jj = 0; jj < 64; ++jj) {
      const float vv = vp[(size_t)jj * 64];
#pragma unroll
      for (int i = 0; i < 8; ++i) acc[i] += pbuf[w][i][jj] * vv;
    }
  }
#pragma unroll
  for (int i = 0; i < 8; ++i)
    ctxb[((size_t)(b_ * 1024 + r0 + rb + i)) * 768 + h * 64 + l] = (__bf16)acc[i];
}

// --- 6. proj GEMM: out = ctxb @ pwb.T + bias; bias-only when keep==0 -------
__global__ __launch_bounds__(256) void kg_proj(
    const __bf16* __restrict__ A, const __bf16* __restrict__ Bm,
    const float* __restrict__ bias, const int* __restrict__ keepCnt,
    float* __restrict__ out)
{
  const int tid = threadIdx.x;
  const int w = tid >> 6, lane = tid & 63, quad = lane >> 4, l = lane & 15;
  const int r0 = blockIdx.y * 64, c0 = blockIdx.x * 64;
  if (*keepCnt == 0) {  // ctx == 0 -> out = bias (uniform branch)
#pragma unroll
    for (int ct = 0; ct < 4; ++ct) {
      const int c = c0 + ct * 16 + l;
      const float bv = bias[c];
#pragma unroll
      for (int i = 0; i < 4; ++i) {
        const int rg = r0 + w * 16 + quad * 4 + i;
        out[(size_t)rg * 768 + c] = bv;
      }
    }
    return;
  }
  __shared__ __bf16 As[64 * 72];
  __shared__ __bf16 Bs[64 * 72];
  const int row = tid >> 3, ko = (tid & 7) * 8;
  const f32x4 zero = {0.f, 0.f, 0.f, 0.f};
  f32x4 acc[4];
#pragma unroll
  for (int ct = 0; ct < 4; ++ct) acc[ct] = zero;

  uint4 a0 = *(const uint4*)(A + (size_t)(r0 + row) * 768 + ko);
  uint4 a1 = *(const uint4*)(A + (size_t)(r0 + row + 32) * 768 + ko);
  uint4 b0 = *(const uint4*)(Bm + (size_t)(c0 + row) * 768 + ko);
  uint4 b1 = *(const uint4*)(Bm + (size_t)(c0 + row + 32) * 768 + ko);

  for (int k0 = 0; k0 < 768; k0 += 64) {
    __syncthreads();
    *(uint4*)&As[row * 72 + ko] = a0;
    *(uint4*)&As[(row + 32) * 72 + ko] = a1;
    *(uint4*)&Bs[row * 72 + ko] = b0;
    *(uint4*)&Bs[(row + 32) * 72 + ko] = b1;
    __syncthreads();
    if (k0 < 704) {
      a0 = *(const uint4*)(A + (size_t)(r0 + row) * 768 + k0 + 64 + ko);
      a1 = *(const uint4*)(A + (size_t)(r0 + row + 32) * 768 + k0 + 64 + ko);
      b0 = *(const uint4*)(Bm + (size_t)(c0 + row) * 768 + k0 + 64 + ko);
      b1 = *(const uint4*)(Bm + (size_t)(c0 + row + 32) * 768 + k0 + 64 + ko);
    }
    const bf16x8 af0 = *(const bf16x8*)&As[(w * 16 + l) * 72 + quad * 8];
    const bf16x8 af1 = *(const bf16x8*)&As[(w * 16 + l) * 72 + 32 + quad * 8];
#pragma unroll
    for (int ct = 0; ct < 4; ++ct) {
      const bf16x8 bf0 = *(const bf16x8*)&Bs[(ct * 16 + l) * 72 + quad * 8];
      const bf16x8 bf1 = *(const bf16x8*)&Bs[(ct * 16 + l) * 72 + 32 + quad * 8];
      acc[ct] = MFMA16(af0, bf0, acc[ct]);
      acc[ct] = MFMA16(af1, bf1, acc[ct]);
    }
  }
#pragma unroll
  for (int ct = 0; ct < 4; ++ct) {
    const int c = c0 + ct * 16 + l;
#pragma unroll
    for (int i = 0; i < 4; ++i) {
      const int rg = r0 + w * 16 + quad * 4 + i;
      out[(size_t)rg * 768 + c] = acc[ct][i] + bias[c];
    }
  }
}

extern "C" void kernel_launch(void* const* d_in, const int* in_sizes, int n_in,
                              void* d_out, int out_size, void* d_ws, size_t ws_size,
                              hipStream_t stream)
{
  const float* x      = (const float*)d_in[0];
  const float* qkv_w  = (const float*)d_in[1];
  const float* proj_w = (const float*)d_in[2];
  const float* proj_b = (const float*)d_in[3];
  const int*   cur_ep = (const int*)d_in[4];

  char* W = (char*)d_ws;
  __bf16* xb    = (__bf16*)(W + 0);
  __bf16* qwb   = (__bf16*)(W + 6291456);
  __bf16* pwb   = (__bf16*)(W + 9830400);
  __bf16* qb    = (__bf16*)(W + 11010048);
  __bf16* kb    = (__bf16*)(W + 17301504);
  float*  v     = (float*) (W + 23592960);
  __bf16* ctxb  = (__bf16*)(W + 36175872);
  float*  lse   = (float*) (W + 42467328);
  float*  mask  = (float*) (W + 42663936);
  int*    keep  = (int*)   (W + 42668032);
  float*  colSP = (float*) (W + 42668544);
  float*  out   = (float*)d_out;

  kc_conv<<<5376, 256, 0, stream>>>(x, qkv_w, proj_w, xb, qwb, pwb, colSP, keep);
  kg_qkv<<<dim3(36, 64), 256, 0, stream>>>(xb, qwb, qb, kb, v);
  ks_fused<<<dim3(48, 16), 256, 0, stream>>>(qb, kb, lse, colSP);
  k_mask<<<1, 1024, 0, stream>>>(colSP, cur_ep, mask, keep);
  k_av<<<dim3(48, 32), 256, 0, stream>>>(qb, kb, v, lse, mask, keep, ctxb);
  kg_proj<<<dim3(12, 64), 256, 0, stream>>>(ctxb, pwb, proj_b, keep, out);
}

// Round 9
// 185.070 us; speedup vs baseline: 1.2159x; 1.1544x over previous
//
#include <hip/hip_runtime.h>

// ---------------------------------------------------------------------------
// EntropyPrunedSelfAttention  (B=4, N=1024, C=768, H=12, hd=64)
// Round 9: r5 skeleton with 128-row stats blocks (grid 48x8). Per barrier-
// stage: 16 MFMA + 64 exp per wave (2x r5) with the SAME 2-uint4 staging that
// the compiler provably pipelines without spilling. Barrier events halved.
//
// Workspace (byte offsets):
//   xb      bf16[4096*768]      @ 0
//   qwb     bf16[2304*768]      @ 6291456
//   pwb     bf16[768*768]       @ 9830400
//   qb      bf16[48*1024*64]    @ 11010048
//   kb      bf16[48*1024*64]    @ 17301504
//   v       f32 [48*1024*64]    @ 23592960
//   ctxb    bf16[4096*768]      @ 36175872
//   lse     f32 [48*1024]       @ 42467328
//   mask    f32 [1024]          @ 42663936
//   keep    int [1]             @ 42668032
//   colSP   f32 [2048]          @ 42668544   (colS[1024] ++ colP[1024])
// total ~42.7 MB
// ---------------------------------------------------------------------------

typedef __bf16 bf16x8 __attribute__((ext_vector_type(8)));
typedef __bf16 bf16x4 __attribute__((ext_vector_type(4)));
typedef float  f32x4  __attribute__((ext_vector_type(4)));

#define MFMA16(a, b, c) __builtin_amdgcn_mfma_f32_16x16x32_bf16((a), (b), (c), 0, 0, 0)
#define LOG2E_8 0.18033688f  /* 0.125 * log2(e) */

// --- 1. fp32 -> bf16 conversion + zero colSP/keepCnt -----------------------
__global__ __launch_bounds__(256) void kc_conv(
    const float* __restrict__ x, const float* __restrict__ qw, const float* __restrict__ pw,
    __bf16* __restrict__ xb, __bf16* __restrict__ qwb, __bf16* __restrict__ pwb,
    float* __restrict__ colSP, int* __restrict__ keepCnt)
{
  const int i = blockIdx.x * 256 + threadIdx.x;
  const float4* src;
  __bf16* dst;
  int j;
  if (i < 786432)       { src = (const float4*)x;  dst = xb;  j = i; }
  else if (i < 1228800) { src = (const float4*)qw; dst = qwb; j = i - 786432; }
  else                  { src = (const float4*)pw; dst = pwb; j = i - 1228800; }
  const float4 f = src[j];
  bf16x4 o;
  o[0] = (__bf16)f.x; o[1] = (__bf16)f.y; o[2] = (__bf16)f.z; o[3] = (__bf16)f.w;
  *(bf16x4*)(dst + 4 * (size_t)j) = o;
  if (i < 2048) colSP[i] = 0.f;
  if (i == 0) *keepCnt = 0;
}

// --- 2. QKV GEMM (software-pipelined): qkv = xb @ qwb.T --------------------
__global__ __launch_bounds__(256) void kg_qkv(
    const __bf16* __restrict__ A, const __bf16* __restrict__ Bm,
    __bf16* __restrict__ qb, __bf16* __restrict__ kb, float* __restrict__ v)
{
  __shared__ __bf16 As[64 * 72];
  __shared__ __bf16 Bs[64 * 72];
  const int tid = threadIdx.x;
  const int w = tid >> 6, lane = tid & 63, quad = lane >> 4, l = lane & 15;
  const int r0 = blockIdx.y * 64, c0 = blockIdx.x * 64;
  const int row = tid >> 3, ko = (tid & 7) * 8;
  const f32x4 zero = {0.f, 0.f, 0.f, 0.f};
  f32x4 acc[4];
#pragma unroll
  for (int ct = 0; ct < 4; ++ct) acc[ct] = zero;

  uint4 a0 = *(const uint4*)(A + (size_t)(r0 + row) * 768 + ko);
  uint4 a1 = *(const uint4*)(A + (size_t)(r0 + row + 32) * 768 + ko);
  uint4 b0 = *(const uint4*)(Bm + (size_t)(c0 + row) * 768 + ko);
  uint4 b1 = *(const uint4*)(Bm + (size_t)(c0 + row + 32) * 768 + ko);

  for (int k0 = 0; k0 < 768; k0 += 64) {
    __syncthreads();
    *(uint4*)&As[row * 72 + ko] = a0;
    *(uint4*)&As[(row + 32) * 72 + ko] = a1;
    *(uint4*)&Bs[row * 72 + ko] = b0;
    *(uint4*)&Bs[(row + 32) * 72 + ko] = b1;
    __syncthreads();
    if (k0 < 704) {
      a0 = *(const uint4*)(A + (size_t)(r0 + row) * 768 + k0 + 64 + ko);
      a1 = *(const uint4*)(A + (size_t)(r0 + row + 32) * 768 + k0 + 64 + ko);
      b0 = *(const uint4*)(Bm + (size_t)(c0 + row) * 768 + k0 + 64 + ko);
      b1 = *(const uint4*)(Bm + (size_t)(c0 + row + 32) * 768 + k0 + 64 + ko);
    }
    const bf16x8 af0 = *(const bf16x8*)&As[(w * 16 + l) * 72 + quad * 8];
    const bf16x8 af1 = *(const bf16x8*)&As[(w * 16 + l) * 72 + 32 + quad * 8];
#pragma unroll
    for (int ct = 0; ct < 4; ++ct) {
      const bf16x8 bf0 = *(const bf16x8*)&Bs[(ct * 16 + l) * 72 + quad * 8];
      const bf16x8 bf1 = *(const bf16x8*)&Bs[(ct * 16 + l) * 72 + 32 + quad * 8];
      acc[ct] = MFMA16(af0, bf0, acc[ct]);
      acc[ct] = MFMA16(af1, bf1, acc[ct]);
    }
  }
  const int part = c0 / 768;
  const int h = (c0 % 768) >> 6;
#pragma unroll
  for (int ct = 0; ct < 4; ++ct) {
    const int d = ct * 16 + l;
#pragma unroll
    for (int i = 0; i < 4; ++i) {
      const int rg = r0 + w * 16 + quad * 4 + i;
      const int b_ = rg >> 10, n = rg & 1023;
      const size_t off = ((size_t)(b_ * 12 + h) * 1024 + n) * 64 + d;
      const float val = acc[ct][i];
      if (part == 0)      qb[off] = (__bf16)val;
      else if (part == 1) kb[off] = (__bf16)val;
      else                v[off]  = val;
    }
  }
}

// --- 3. fused stats, 128-row blocks ----------------------------------------
// grid (48, 8): block = (bh, 128 rows). Wave w owns rows w*32..w*32+31
// (2 row-tiles) and covers all 1024 cols -> Z wave-complete after pass 1.
// Staging identical to r5 (64 K-rows, 2 uint4/thread, reg-prefetched).
__global__ __launch_bounds__(256) void ks_fused(
    const __bf16* __restrict__ qb, const __bf16* __restrict__ kb,
    float* __restrict__ lse, float* __restrict__ colSP)
{
  __shared__ __bf16 Ks[64 * 72];
  __shared__ float sS[1024];
  __shared__ float sP[1024];
  const int tid = threadIdx.x;
  const int w = tid >> 6, lane = tid & 63, quad = lane >> 4, l = lane & 15;
  const int bh = blockIdx.x, r0 = blockIdx.y * 128;
  const int row = tid >> 3, ko = (tid & 7) * 8;
  for (int i = tid; i < 1024; i += 256) { sS[i] = 0.f; sP[i] = 0.f; }

  const __bf16* qbase = qb + ((size_t)bh * 1024 + r0 + w * 32 + l) * 64;
  bf16x8 aq0[2], aq1[2];
#pragma unroll
  for (int rt = 0; rt < 2; ++rt) {
    aq0[rt] = *(const bf16x8*)(qbase + (size_t)rt * 16 * 64 + quad * 8);
    aq1[rt] = *(const bf16x8*)(qbase + (size_t)rt * 16 * 64 + 32 + quad * 8);
  }
  const __bf16* kbase = kb + (size_t)bh * 65536;  // [1024][64]
  const f32x4 zero = {0.f, 0.f, 0.f, 0.f};

  uint4 ka0 = *(const uint4*)(kbase + (size_t)row * 64 + ko);
  uint4 ka1 = *(const uint4*)(kbase + (size_t)(row + 32) * 64 + ko);

  float z[8] = {};
  // ---- pass 1: row sums of exp ----
  for (int chunk = 0; chunk < 16; ++chunk) {
    __syncthreads();
    *(uint4*)&Ks[row * 72 + ko] = ka0;
    *(uint4*)&Ks[(row + 32) * 72 + ko] = ka1;
    __syncthreads();
    const int nxt = (chunk < 15) ? (chunk + 1) : 0;  // chunk 15 prefetches pass-2 chunk 0
    ka0 = *(const uint4*)(kbase + (size_t)(nxt * 64 + row) * 64 + ko);
    ka1 = *(const uint4*)(kbase + (size_t)(nxt * 64 + row + 32) * 64 + ko);
#pragma unroll
    for (int ct = 0; ct < 4; ++ct) {
      const bf16x8 kf0 = *(const bf16x8*)&Ks[(ct * 16 + l) * 72 + quad * 8];
      const bf16x8 kf1 = *(const bf16x8*)&Ks[(ct * 16 + l) * 72 + 32 + quad * 8];
#pragma unroll
      for (int rt = 0; rt < 2; ++rt) {
        f32x4 acc = MFMA16(aq0[rt], kf0, zero);
        acc = MFMA16(aq1[rt], kf1, acc);
#pragma unroll
        for (int r = 0; r < 4; ++r) z[rt * 4 + r] += exp2f(acc[r] * LOG2E_8);
      }
    }
  }
  // reduce over the 16 column-lanes (within quad group)
#pragma unroll
  for (int off = 1; off < 16; off <<= 1) {
#pragma unroll
    for (int i = 0; i < 8; ++i) z[i] += __shfl_xor(z[i], off);
  }
  float uu[8], ww[8];
#pragma unroll
  for (int i = 0; i < 8; ++i) {
    const float lg = __logf(z[i]);
    uu[i] = 1.0f / z[i];
    ww[i] = lg * uu[i];
    z[i] = lg;  // reuse as lse value
  }
  if (l == 0) {
#pragma unroll
    for (int rt = 0; rt < 2; ++rt)
#pragma unroll
      for (int r = 0; r < 4; ++r)
        lse[bh * 1024 + r0 + w * 32 + rt * 16 + quad * 4 + r] = z[rt * 4 + r];
  }

  // ---- pass 2: column sums of p and p*logp ----
  for (int chunk = 0; chunk < 16; ++chunk) {
    __syncthreads();
    *(uint4*)&Ks[row * 72 + ko] = ka0;
    *(uint4*)&Ks[(row + 32) * 72 + ko] = ka1;
    __syncthreads();
    if (chunk < 15) {
      ka0 = *(const uint4*)(kbase + (size_t)((chunk + 1) * 64 + row) * 64 + ko);
      ka1 = *(const uint4*)(kbase + (size_t)((chunk + 1) * 64 + row + 32) * 64 + ko);
    }
#pragma unroll
    for (int ct = 0; ct < 4; ++ct) {
      const bf16x8 kf0 = *(const bf16x8*)&Ks[(ct * 16 + l) * 72 + quad * 8];
      const bf16x8 kf1 = *(const bf16x8*)&Ks[(ct * 16 + l) * 72 + 32 + quad * 8];
      float cs = 0.f, cp = 0.f;
#pragma unroll
      for (int rt = 0; rt < 2; ++rt) {
        f32x4 acc = MFMA16(aq0[rt], kf0, zero);
        acc = MFMA16(aq1[rt], kf1, acc);
#pragma unroll
        for (int r = 0; r < 4; ++r) {
          const float sg = acc[r] * 0.125f;
          const float e = exp2f(acc[r] * LOG2E_8);
          const float t = e * uu[rt * 4 + r];
          cs += t;
          cp += t * sg - e * ww[rt * 4 + r];
        }
      }
      // sum the 4 quad groups (rows) -> lanes<16 hold column partials
      cs += __shfl_xor(cs, 16); cs += __shfl_xor(cs, 32);
      cp += __shfl_xor(cp, 16); cp += __shfl_xor(cp, 32);
      if (lane < 16) {
        atomicAdd(&sS[chunk * 64 + ct * 16 + l], cs);  // 4-way (waves), LDS
        atomicAdd(&sP[chunk * 64 + ct * 16 + l], cp);
      }
    }
  }
  __syncthreads();
  for (int i = tid; i < 1024; i += 256) {
    atomicAdd(&colSP[i], sS[i]);          // 8 row-blocks per address
    atomicAdd(&colSP[1024 + i], sP[i]);
  }
}

// --- 4. entropy -> mask + keepCnt ------------------------------------------
__global__ void k_mask(const float* __restrict__ colSP, const int* __restrict__ cur_epoch,
                       float* __restrict__ mask, int* __restrict__ keepCnt)
{
  const int j = threadIdx.x;
  const float s = colSP[j];
  const float ent = __logf(s) - colSP[1024 + j] / s;
  const int ce = cur_epoch[0];
  float factor = 0.f;
  for (int i = 1; i <= ce; ++i) factor += __expf(-(float)i);
  factor *= 5.0f;
  const float thr = __logf(768.0f) - factor;
  const int keep = (ent <= thr) ? 1 : 0;
  mask[j] = keep ? 1.0f : 0.0f;
  if (keep) atomicAdd(keepCnt, 1);
}

// --- 5. masked AV -> ctxb (bf16). No-op when no column survives. -----------
__global__ __launch_bounds__(256) void k_av(
    const __bf16* __restrict__ qb, const __bf16* __restrict__ kb,
    const float* __restrict__ v, const float* __restrict__ lse,
    const float* __restrict__ mask, const int* __restrict__ keepCnt,
    __bf16* __restrict__ ctxb)
{
  if (*keepCnt == 0) return;  // ctxb unused downstream in this case
  const int tid = threadIdx.x;
  const int bh = blockIdx.x, r0 = blockIdx.y * 32;
  const int b_ = bh / 12, h = bh % 12;
  __shared__ float qs[32][64];
  __shared__ float pbuf[4][8][64];
  for (int i = tid; i < 2048; i += 256)
    qs[i >> 6][i & 63] = (float)qb[((size_t)bh * 1024 + r0) * 64 + i];
  __syncthreads();
  const int w = tid >> 6, l = tid & 63, rb = w * 8;
  float ls[8];
#pragma unroll
  for (int i = 0; i < 8; ++i) ls[i] = lse[bh * 1024 + r0 + rb + i];
  float acc[8] = {};
  for (int chunk = 0; chunk < 16; ++chunk) {
    const float mk = mask[chunk * 64 + l];
    if (__ballot(mk != 0.0f) == 0ull) continue;  // block-uniform
    const __bf16* kp = kb + ((size_t)bh * 1024 + chunk * 64 + l) * 64;
    float s[8] = {};
    for (int d0 = 0; d0 < 64; d0 += 8) {
      const bf16x8 kf = *(const bf16x8*)(kp + d0);
#pragma unroll
      for (int dd = 0; dd < 8; ++dd) {
        const float kv = (float)kf[dd];
#pragma unroll
        for (int i = 0; i < 8; ++i) s[i] += qs[rb + i][d0 + dd] * kv;
      }
    }
    __syncthreads();
#pragma unroll
    for (int i = 0; i < 8; ++i)
      pbuf[w][i][l] = __expf(s[i] * 0.125f - ls[i]) * mk;
    __syncthreads();
    const float* vp = v + ((size_t)bh * 1024 + chunk * 64) * 64 + l;
    for (int jj = 0; jj < 64; ++jj) {
      const float vv = vp[(size_t)jj * 64];
#pragma unroll
      for (int i = 0; i < 8; ++i) acc[i] += pbuf[w][i][jj] * vv;
    }
  }
#pragma unroll
  for (int i = 0; i < 8; ++i)
    ctxb[((size_t)(b_ * 1024 + r0 + rb + i)) * 768 + h * 64 + l] = (__bf16)acc[i];
}

// --- 6. proj GEMM: out = ctxb @ pwb.T + bias; bias-only when keep==0 -------
__global__ __launch_bounds__(256) void kg_proj(
    const __bf16* __restrict__ A, const __bf16* __restrict__ Bm,
    const float* __restrict__ bias, const int* __restrict__ keepCnt,
    float* __restrict__ out)
{
  const int tid = threadIdx.x;
  const int w = tid >> 6, lane = tid & 63, quad = lane >> 4, l = lane & 15;
  const int r0 = blockIdx.y * 64, c0 = blockIdx.x * 64;
  if (*keepCnt == 0) {  // ctx == 0 -> out = bias (uniform branch)
#pragma unroll
    for (int ct = 0; ct < 4; ++ct) {
      const int c = c0 + ct * 16 + l;
      const float bv = bias[c];
#pragma unroll
      for (int i = 0; i < 4; ++i) {
        const int rg = r0 + w * 16 + quad * 4 + i;
        out[(size_t)rg * 768 + c] = bv;
      }
    }
    return;
  }
  __shared__ __bf16 As[64 * 72];
  __shared__ __bf16 Bs[64 * 72];
  const int row = tid >> 3, ko = (tid & 7) * 8;
  const f32x4 zero = {0.f, 0.f, 0.f, 0.f};
  f32x4 acc[4];
#pragma unroll
  for (int ct = 0; ct < 4; ++ct) acc[ct] = zero;

  uint4 a0 = *(const uint4*)(A + (size_t)(r0 + row) * 768 + ko);
  uint4 a1 = *(const uint4*)(A + (size_t)(r0 + row + 32) * 768 + ko);
  uint4 b0 = *(const uint4*)(Bm + (size_t)(c0 + row) * 768 + ko);
  uint4 b1 = *(const uint4*)(Bm + (size_t)(c0 + row + 32) * 768 + ko);

  for (int k0 = 0; k0 < 768; k0 += 64) {
    __syncthreads();
    *(uint4*)&As[row * 72 + ko] = a0;
    *(uint4*)&As[(row + 32) * 72 + ko] = a1;
    *(uint4*)&Bs[row * 72 + ko] = b0;
    *(uint4*)&Bs[(row + 32) * 72 + ko] = b1;
    __syncthreads();
    if (k0 < 704) {
      a0 = *(const uint4*)(A + (size_t)(r0 + row) * 768 + k0 + 64 + ko);
      a1 = *(const uint4*)(A + (size_t)(r0 + row + 32) * 768 + k0 + 64 + ko);
      b0 = *(const uint4*)(Bm + (size_t)(c0 + row) * 768 + k0 + 64 + ko);
      b1 = *(const uint4*)(Bm + (size_t)(c0 + row + 32) * 768 + k0 + 64 + ko);
    }
    const bf16x8 af0 = *(const bf16x8*)&As[(w * 16 + l) * 72 + quad * 8];
    const bf16x8 af1 = *(const bf16x8*)&As[(w * 16 + l) * 72 + 32 + quad * 8];
#pragma unroll
    for (int ct = 0; ct < 4; ++ct) {
      const bf16x8 bf0 = *(const bf16x8*)&Bs[(ct * 16 + l) * 72 + quad * 8];
      const bf16x8 bf1 = *(const bf16x8*)&Bs[(ct * 16 + l) * 72 + 32 + quad * 8];
      acc[ct] = MFMA16(af0, bf0, acc[ct]);
      acc[ct] = MFMA16(af1, bf1, acc[ct]);
    }
  }
#pragma unroll
  for (int ct = 0; ct < 4; ++ct) {
    const int c = c0 + ct * 16 + l;
#pragma unroll
    for (int i = 0; i < 4; ++i) {
      const int rg = r0 + w * 16 + quad * 4 + i;
      out[(size_t)rg * 768 + c] = acc[ct][i] + bias[c];
    }
  }
}

extern "C" void kernel_launch(void* const* d_in, const int* in_sizes, int n_in,
                              void* d_out, int out_size, void* d_ws, size_t ws_size,
                              hipStream_t stream)
{
  const float* x      = (const float*)d_in[0];
  const float* qkv_w  = (const float*)d_in[1];
  const float* proj_w = (const float*)d_in[2];
  const float* proj_b = (const float*)d_in[3];
  const int*   cur_ep = (const int*)d_in[4];

  char* W = (char*)d_ws;
  __bf16* xb    = (__bf16*)(W + 0);
  __bf16* qwb   = (__bf16*)(W + 6291456);
  __bf16* pwb   = (__bf16*)(W + 9830400);
  __bf16* qb    = (__bf16*)(W + 11010048);
  __bf16* kb    = (__bf16*)(W + 17301504);
  float*  v     = (float*) (W + 23592960);
  __bf16* ctxb  = (__bf16*)(W + 36175872);
  float*  lse   = (float*) (W + 42467328);
  float*  mask  = (float*) (W + 42663936);
  int*    keep  = (int*)   (W + 42668032);
  float*  colSP = (float*) (W + 42668544);
  float*  out   = (float*)d_out;

  kc_conv<<<5376, 256, 0, stream>>>(x, qkv_w, proj_w, xb, qwb, pwb, colSP, keep);
  kg_qkv<<<dim3(36, 64), 256, 0, stream>>>(xb, qwb, qb, kb, v);
  ks_fused<<<dim3(48, 8), 256, 0, stream>>>(qb, kb, lse, colSP);
  k_mask<<<1, 1024, 0, stream>>>(colSP, cur_ep, mask, keep);
  k_av<<<dim3(48, 32), 256, 0, stream>>>(qb, kb, v, lse, mask, keep, ctxb);
  kg_proj<<<dim3(12, 64), 256, 0, stream>>>(ctxb, pwb, proj_b, keep, out);
}

// Round 10
// 166.788 us; speedup vs baseline: 1.3492x; 1.1096x over previous
//
#include <hip/hip_runtime.h>

// ---------------------------------------------------------------------------
// EntropyPrunedSelfAttention  (B=4, N=1024, C=768, H=12, hd=64)
// Round 10: ks_fused v2 — wave-per-column-tile (8 MFMA per kf read-pair,
// LDS reads 32->8 per stage), double-buffered Ks with ONE barrier per stage
// ordered [write | barrier | prefetch | compute] so the barrier never drains
// an in-flight prefetch. zrow LDS combine for cross-wave Z; pass-2 column
// partials are contention-free plain LDS accumulates.
//
// Workspace (byte offsets):
//   xb      bf16[4096*768]      @ 0
//   qwb     bf16[2304*768]      @ 6291456
//   pwb     bf16[768*768]       @ 9830400
//   qb      bf16[48*1024*64]    @ 11010048
//   kb      bf16[48*1024*64]    @ 17301504
//   v       f32 [48*1024*64]    @ 23592960
//   ctxb    bf16[4096*768]      @ 36175872
//   lse     f32 [48*1024]       @ 42467328
//   mask    f32 [1024]          @ 42663936
//   keep    int [1]             @ 42668032
//   colSP   f32 [2048]          @ 42668544   (colS[1024] ++ colP[1024])
// total ~42.7 MB
// ---------------------------------------------------------------------------

typedef __bf16 bf16x8 __attribute__((ext_vector_type(8)));
typedef __bf16 bf16x4 __attribute__((ext_vector_type(4)));
typedef float  f32x4  __attribute__((ext_vector_type(4)));

#define MFMA16(a, b, c) __builtin_amdgcn_mfma_f32_16x16x32_bf16((a), (b), (c), 0, 0, 0)
#define LOG2E_8 0.18033688f  /* 0.125 * log2(e) */

// --- 1. fp32 -> bf16 conversion + zero colSP/keepCnt -----------------------
__global__ __launch_bounds__(256) void kc_conv(
    const float* __restrict__ x, const float* __restrict__ qw, const float* __restrict__ pw,
    __bf16* __restrict__ xb, __bf16* __restrict__ qwb, __bf16* __restrict__ pwb,
    float* __restrict__ colSP, int* __restrict__ keepCnt)
{
  const int i = blockIdx.x * 256 + threadIdx.x;
  const float4* src;
  __bf16* dst;
  int j;
  if (i < 786432)       { src = (const float4*)x;  dst = xb;  j = i; }
  else if (i < 1228800) { src = (const float4*)qw; dst = qwb; j = i - 786432; }
  else                  { src = (const float4*)pw; dst = pwb; j = i - 1228800; }
  const float4 f = src[j];
  bf16x4 o;
  o[0] = (__bf16)f.x; o[1] = (__bf16)f.y; o[2] = (__bf16)f.z; o[3] = (__bf16)f.w;
  *(bf16x4*)(dst + 4 * (size_t)j) = o;
  if (i < 2048) colSP[i] = 0.f;
  if (i == 0) *keepCnt = 0;
}

// --- 2. QKV GEMM (software-pipelined): qkv = xb @ qwb.T --------------------
__global__ __launch_bounds__(256) void kg_qkv(
    const __bf16* __restrict__ A, const __bf16* __restrict__ Bm,
    __bf16* __restrict__ qb, __bf16* __restrict__ kb, float* __restrict__ v)
{
  __shared__ __bf16 As[64 * 72];
  __shared__ __bf16 Bs[64 * 72];
  const int tid = threadIdx.x;
  const int w = tid >> 6, lane = tid & 63, quad = lane >> 4, l = lane & 15;
  const int r0 = blockIdx.y * 64, c0 = blockIdx.x * 64;
  const int row = tid >> 3, ko = (tid & 7) * 8;
  const f32x4 zero = {0.f, 0.f, 0.f, 0.f};
  f32x4 acc[4];
#pragma unroll
  for (int ct = 0; ct < 4; ++ct) acc[ct] = zero;

  uint4 a0 = *(const uint4*)(A + (size_t)(r0 + row) * 768 + ko);
  uint4 a1 = *(const uint4*)(A + (size_t)(r0 + row + 32) * 768 + ko);
  uint4 b0 = *(const uint4*)(Bm + (size_t)(c0 + row) * 768 + ko);
  uint4 b1 = *(const uint4*)(Bm + (size_t)(c0 + row + 32) * 768 + ko);

  for (int k0 = 0; k0 < 768; k0 += 64) {
    __syncthreads();
    *(uint4*)&As[row * 72 + ko] = a0;
    *(uint4*)&As[(row + 32) * 72 + ko] = a1;
    *(uint4*)&Bs[row * 72 + ko] = b0;
    *(uint4*)&Bs[(row + 32) * 72 + ko] = b1;
    __syncthreads();
    if (k0 < 704) {
      a0 = *(const uint4*)(A + (size_t)(r0 + row) * 768 + k0 + 64 + ko);
      a1 = *(const uint4*)(A + (size_t)(r0 + row + 32) * 768 + k0 + 64 + ko);
      b0 = *(const uint4*)(Bm + (size_t)(c0 + row) * 768 + k0 + 64 + ko);
      b1 = *(const uint4*)(Bm + (size_t)(c0 + row + 32) * 768 + k0 + 64 + ko);
    }
    const bf16x8 af0 = *(const bf16x8*)&As[(w * 16 + l) * 72 + quad * 8];
    const bf16x8 af1 = *(const bf16x8*)&As[(w * 16 + l) * 72 + 32 + quad * 8];
#pragma unroll
    for (int ct = 0; ct < 4; ++ct) {
      const bf16x8 bf0 = *(const bf16x8*)&Bs[(ct * 16 + l) * 72 + quad * 8];
      const bf16x8 bf1 = *(const bf16x8*)&Bs[(ct * 16 + l) * 72 + 32 + quad * 8];
      acc[ct] = MFMA16(af0, bf0, acc[ct]);
      acc[ct] = MFMA16(af1, bf1, acc[ct]);
    }
  }
  const int part = c0 / 768;
  const int h = (c0 % 768) >> 6;
#pragma unroll
  for (int ct = 0; ct < 4; ++ct) {
    const int d = ct * 16 + l;
#pragma unroll
    for (int i = 0; i < 4; ++i) {
      const int rg = r0 + w * 16 + quad * 4 + i;
      const int b_ = rg >> 10, n = rg & 1023;
      const size_t off = ((size_t)(b_ * 12 + h) * 1024 + n) * 64 + d;
      const float val = acc[ct][i];
      if (part == 0)      qb[off] = (__bf16)val;
      else if (part == 1) kb[off] = (__bf16)val;
      else                v[off]  = val;
    }
  }
}

// --- 3. fused stats v2 ------------------------------------------------------
// grid (48, 16): block = (bh, 64 rows) x 1024 cols. Wave w owns column-tile
// ct=w of every chunk; all 4 Q row-tiles resident in regs (8 MFMA / kf pair).
// Double-buffered Ks, one barrier per stage: write | barrier | prefetch |
// compute. Cross-wave Z via zrow LDS; pass-2 partials contention-free.
__global__ __launch_bounds__(256) void ks_fused(
    const __bf16* __restrict__ qb, const __bf16* __restrict__ kb,
    float* __restrict__ lse, float* __restrict__ colSP)
{
  __shared__ __bf16 Ks[2][64 * 72];
  __shared__ float sS[1024];
  __shared__ float sP[1024];
  __shared__ float zrow[64];
  const int tid = threadIdx.x;
  const int w = tid >> 6, lane = tid & 63, quad = lane >> 4, l = lane & 15;
  const int bh = blockIdx.x, r0 = blockIdx.y * 64;
  const int row = tid >> 3, ko = (tid & 7) * 8;
  for (int i = tid; i < 1024; i += 256) { sS[i] = 0.f; sP[i] = 0.f; }
  if (tid < 64) zrow[tid] = 0.f;

  // 4 Q row-tiles resident (A-operand: m = l, k = quad*8+j / +32)
  const __bf16* qbase = qb + ((size_t)bh * 1024 + r0 + l) * 64;
  bf16x8 aq0[4], aq1[4];
#pragma unroll
  for (int rt = 0; rt < 4; ++rt) {
    aq0[rt] = *(const bf16x8*)(qbase + rt * 1024 + quad * 8);
    aq1[rt] = *(const bf16x8*)(qbase + rt * 1024 + 32 + quad * 8);
  }
  const __bf16* kbase = kb + (size_t)bh * 65536;  // [1024][64]
  const f32x4 zero = {0.f, 0.f, 0.f, 0.f};
  const int koff = (w * 16 + l) * 72 + quad * 8;

  uint4 ka0 = *(const uint4*)(kbase + (size_t)row * 64 + ko);
  uint4 ka1 = *(const uint4*)(kbase + (size_t)(row + 32) * 64 + ko);

  float z[16] = {};
  // ---- pass 1: row sums of exp ----
  for (int s = 0; s < 16; ++s) {
    __bf16* Kw = Ks[s & 1];
    *(uint4*)&Kw[row * 72 + ko] = ka0;
    *(uint4*)&Kw[(row + 32) * 72 + ko] = ka1;
    __syncthreads();  // chunk s visible; no vmem in flight here
    const int nxt = (s + 1) & 15;  // s==15 prefetches chunk 0 for pass 2
    ka0 = *(const uint4*)(kbase + (size_t)(nxt * 64 + row) * 64 + ko);
    ka1 = *(const uint4*)(kbase + (size_t)(nxt * 64 + row + 32) * 64 + ko);
    const bf16x8 kf0 = *(const bf16x8*)&Kw[koff];
    const bf16x8 kf1 = *(const bf16x8*)&Kw[koff + 32];
#pragma unroll
    for (int rt = 0; rt < 4; ++rt) {
      f32x4 acc = MFMA16(aq0[rt], kf0, zero);
      acc = MFMA16(aq1[rt], kf1, acc);
#pragma unroll
      for (int r = 0; r < 4; ++r) z[rt * 4 + r] += exp2f(acc[r] * LOG2E_8);
    }
  }
  // reduce over the 16 column lanes (stays within quad group)
#pragma unroll
  for (int off = 1; off < 16; off <<= 1) {
#pragma unroll
    for (int i = 0; i < 16; ++i) z[i] += __shfl_xor(z[i], off);
  }
  if (l == 0) {
#pragma unroll
    for (int rt = 0; rt < 4; ++rt)
#pragma unroll
      for (int r = 0; r < 4; ++r)
        atomicAdd(&zrow[rt * 16 + quad * 4 + r], z[rt * 4 + r]);
  }
  __syncthreads();  // zrow complete
  if (tid < 64) lse[bh * 1024 + r0 + tid] = __logf(zrow[tid]);
  float uu[16], ww[16];
#pragma unroll
  for (int rt = 0; rt < 4; ++rt) {
#pragma unroll
    for (int r = 0; r < 4; ++r) {
      const float Z = zrow[rt * 16 + quad * 4 + r];
      const float lg = __logf(Z);
      uu[rt * 4 + r] = 1.0f / Z;
      ww[rt * 4 + r] = lg / Z;
    }
  }

  // ---- pass 2: column sums of p and p*logp ----
  for (int s = 0; s < 16; ++s) {
    __bf16* Kw = Ks[s & 1];
    *(uint4*)&Kw[row * 72 + ko] = ka0;
    *(uint4*)&Kw[(row + 32) * 72 + ko] = ka1;
    __syncthreads();
    if (s < 15) {
      ka0 = *(const uint4*)(kbase + (size_t)((s + 1) * 64 + row) * 64 + ko);
      ka1 = *(const uint4*)(kbase + (size_t)((s + 1) * 64 + row + 32) * 64 + ko);
    }
    const bf16x8 kf0 = *(const bf16x8*)&Kw[koff];
    const bf16x8 kf1 = *(const bf16x8*)&Kw[koff + 32];
    float cs = 0.f, cp = 0.f;
#pragma unroll
    for (int rt = 0; rt < 4; ++rt) {
      f32x4 acc = MFMA16(aq0[rt], kf0, zero);
      acc = MFMA16(aq1[rt], kf1, acc);
#pragma unroll
      for (int r = 0; r < 4; ++r) {
        const float sg = acc[r] * 0.125f;
        const float e = exp2f(acc[r] * LOG2E_8);
        const float t = e * uu[rt * 4 + r];
        cs += t;
        cp += t * sg - e * ww[rt * 4 + r];
      }
    }
    // reduce over the 4 quad groups (rows); every lane ends with the total
    cs += __shfl_xor(cs, 16); cs += __shfl_xor(cs, 32);
    cp += __shfl_xor(cp, 16); cp += __shfl_xor(cp, 32);
    if (lane < 16) {  // wave-private columns: plain LDS accumulate, no atomics
      sS[s * 64 + w * 16 + l] += cs;
      sP[s * 64 + w * 16 + l] += cp;
    }
  }
  __syncthreads();
  for (int i = tid; i < 1024; i += 256) {
    atomicAdd(&colSP[i], sS[i]);          // 16 row-blocks per address
    atomicAdd(&colSP[1024 + i], sP[i]);
  }
}

// --- 4. entropy -> mask + keepCnt ------------------------------------------
__global__ void k_mask(const float* __restrict__ colSP, const int* __restrict__ cur_epoch,
                       float* __restrict__ mask, int* __restrict__ keepCnt)
{
  const int j = threadIdx.x;
  const float s = colSP[j];
  const float ent = __logf(s) - colSP[1024 + j] / s;
  const int ce = cur_epoch[0];
  float factor = 0.f;
  for (int i = 1; i <= ce; ++i) factor += __expf(-(float)i);
  factor *= 5.0f;
  const float thr = __logf(768.0f) - factor;
  const int keep = (ent <= thr) ? 1 : 0;
  mask[j] = keep ? 1.0f : 0.0f;
  if (keep) atomicAdd(keepCnt, 1);
}

// --- 5. masked AV -> ctxb (bf16). No-op when no column survives. -----------
__global__ __launch_bounds__(256) void k_av(
    const __bf16* __restrict__ qb, const __bf16* __restrict__ kb,
    const float* __restrict__ v, const float* __restrict__ lse,
    const float* __restrict__ mask, const int* __restrict__ keepCnt,
    __bf16* __restrict__ ctxb)
{
  if (*keepCnt == 0) return;  // ctxb unused downstream in this case
  const int tid = threadIdx.x;
  const int bh = blockIdx.x, r0 = blockIdx.y * 32;
  const int b_ = bh / 12, h = bh % 12;
  __shared__ float qs[32][64];
  __shared__ float pbuf[4][8][64];
  for (int i = tid; i < 2048; i += 256)
    qs[i >> 6][i & 63] = (float)qb[((size_t)bh * 1024 + r0) * 64 + i];
  __syncthreads();
  const int w = tid >> 6, l = tid & 63, rb = w * 8;
  float ls[8];
#pragma unroll
  for (int i = 0; i < 8; ++i) ls[i] = lse[bh * 1024 + r0 + rb + i];
  float acc[8] = {};
  for (int chunk = 0; chunk < 16; ++chunk) {
    const float mk = mask[chunk * 64 + l];
    if (__ballot(mk != 0.0f) == 0ull) continue;  // block-uniform
    const __bf16* kp = kb + ((size_t)bh * 1024 + chunk * 64 + l) * 64;
    float s[8] = {};
    for (int d0 = 0; d0 < 64; d0 += 8) {
      const bf16x8 kf = *(const bf16x8*)(kp + d0);
#pragma unroll
      for (int dd = 0; dd < 8; ++dd) {
        const float kv = (float)kf[dd];
#pragma unroll
        for (int i = 0; i < 8; ++i) s[i] += qs[rb + i][d0 + dd] * kv;
      }
    }
    __syncthreads();
#pragma unroll
    for (int i = 0; i < 8; ++i)
      pbuf[w][i][l] = __expf(s[i] * 0.125f - ls[i]) * mk;
    __syncthreads();
    const float* vp = v + ((size_t)bh * 1024 + chunk * 64) * 64 + l;
    for (int jj = 0; jj < 64; ++jj) {
      const float vv = vp[(size_t)jj * 64];
#pragma unroll
      for (int i = 0; i < 8; ++i) acc[i] += pbuf[w][i][jj] * vv;
    }
  }
#pragma unroll
  for (int i = 0; i < 8; ++i)
    ctxb[((size_t)(b_ * 1024 + r0 + rb + i)) * 768 + h * 64 + l] = (__bf16)acc[i];
}

// --- 6. proj GEMM: out = ctxb @ pwb.T + bias; bias-only when keep==0 -------
__global__ __launch_bounds__(256) void kg_proj(
    const __bf16* __restrict__ A, const __bf16* __restrict__ Bm,
    const float* __restrict__ bias, const int* __restrict__ keepCnt,
    float* __restrict__ out)
{
  const int tid = threadIdx.x;
  const int w = tid >> 6, lane = tid & 63, quad = lane >> 4, l = lane & 15;
  const int r0 = blockIdx.y * 64, c0 = blockIdx.x * 64;
  if (*keepCnt == 0) {  // ctx == 0 -> out = bias (uniform branch)
#pragma unroll
    for (int ct = 0; ct < 4; ++ct) {
      const int c = c0 + ct * 16 + l;
      const float bv = bias[c];
#pragma unroll
      for (int i = 0; i < 4; ++i) {
        const int rg = r0 + w * 16 + quad * 4 + i;
        out[(size_t)rg * 768 + c] = bv;
      }
    }
    return;
  }
  __shared__ __bf16 As[64 * 72];
  __shared__ __bf16 Bs[64 * 72];
  const int row = tid >> 3, ko = (tid & 7) * 8;
  const f32x4 zero = {0.f, 0.f, 0.f, 0.f};
  f32x4 acc[4];
#pragma unroll
  for (int ct = 0; ct < 4; ++ct) acc[ct] = zero;

  uint4 a0 = *(const uint4*)(A + (size_t)(r0 + row) * 768 + ko);
  uint4 a1 = *(const uint4*)(A + (size_t)(r0 + row + 32) * 768 + ko);
  uint4 b0 = *(const uint4*)(Bm + (size_t)(c0 + row) * 768 + ko);
  uint4 b1 = *(const uint4*)(Bm + (size_t)(c0 + row + 32) * 768 + ko);

  for (int k0 = 0; k0 < 768; k0 += 64) {
    __syncthreads();
    *(uint4*)&As[row * 72 + ko] = a0;
    *(uint4*)&As[(row + 32) * 72 + ko] = a1;
    *(uint4*)&Bs[row * 72 + ko] = b0;
    *(uint4*)&Bs[(row + 32) * 72 + ko] = b1;
    __syncthreads();
    if (k0 < 704) {
      a0 = *(const uint4*)(A + (size_t)(r0 + row) * 768 + k0 + 64 + ko);
      a1 = *(const uint4*)(A + (size_t)(r0 + row + 32) * 768 + k0 + 64 + ko);
      b0 = *(const uint4*)(Bm + (size_t)(c0 + row) * 768 + k0 + 64 + ko);
      b1 = *(const uint4*)(Bm + (size_t)(c0 + row + 32) * 768 + k0 + 64 + ko);
    }
    const bf16x8 af0 = *(const bf16x8*)&As[(w * 16 + l) * 72 + quad * 8];
    const bf16x8 af1 = *(const bf16x8*)&As[(w * 16 + l) * 72 + 32 + quad * 8];
#pragma unroll
    for (int ct = 0; ct < 4; ++ct) {
      const bf16x8 bf0 = *(const bf16x8*)&Bs[(ct * 16 + l) * 72 + quad * 8];
      const bf16x8 bf1 = *(const bf16x8*)&Bs[(ct * 16 + l) * 72 + 32 + quad * 8];
      acc[ct] = MFMA16(af0, bf0, acc[ct]);
      acc[ct] = MFMA16(af1, bf1, acc[ct]);
    }
  }
#pragma unroll
  for (int ct = 0; ct < 4; ++ct) {
    const int c = c0 + ct * 16 + l;
#pragma unroll
    for (int i = 0; i < 4; ++i) {
      const int rg = r0 + w * 16 + quad * 4 + i;
      out[(size_t)rg * 768 + c] = acc[ct][i] + bias[c];
    }
  }
}

extern "C" void kernel_launch(void* const* d_in, const int* in_sizes, int n_in,
                              void* d_out, int out_size, void* d_ws, size_t ws_size,
                              hipStream_t stream)
{
  const float* x      = (const float*)d_in[0];
  const float* qkv_w  = (const float*)d_in[1];
  const float* proj_w = (const float*)d_in[2];
  const float* proj_b = (const float*)d_in[3];
  const int*   cur_ep = (const int*)d_in[4];

  char* W = (char*)d_ws;
  __bf16* xb    = (__bf16*)(W + 0);
  __bf16* qwb   = (__bf16*)(W + 6291456);
  __bf16* pwb   = (__bf16*)(W + 9830400);
  __bf16* qb    = (__bf16*)(W + 11010048);
  __bf16* kb    = (__bf16*)(W + 17301504);
  float*  v     = (float*) (W + 23592960);
  __bf16* ctxb  = (__bf16*)(W + 36175872);
  float*  lse   = (float*) (W + 42467328);
  float*  mask  = (float*) (W + 42663936);
  int*    keep  = (int*)   (W + 42668032);
  float*  colSP = (float*) (W + 42668544);
  float*  out   = (float*)d_out;

  kc_conv<<<5376, 256, 0, stream>>>(x, qkv_w, proj_w, xb, qwb, pwb, colSP, keep);
  kg_qkv<<<dim3(36, 64), 256, 0, stream>>>(xb, qwb, qb, kb, v);
  ks_fused<<<dim3(48, 16), 256, 0, stream>>>(qb, kb, lse, colSP);
  k_mask<<<1, 1024, 0, stream>>>(colSP, cur_ep, mask, keep);
  k_av<<<dim3(48, 32), 256, 0, stream>>>(qb, kb, v, lse, mask, keep, ctxb);
  kg_proj<<<dim3(12, 64), 256, 0, stream>>>(ctxb, pwb, proj_b, keep, out);
}

// Round 11
// 161.516 us; speedup vs baseline: 1.3933x; 1.0326x over previous
//
#include <hip/hip_runtime.h>

// ---------------------------------------------------------------------------
// EntropyPrunedSelfAttention  (B=4, N=1024, C=768, H=12, hd=64)
// Round 11: (a) kg_qkv rewritten m97-style: 128x128 tile, global_load_lds
// width-16 async staging (no VGPR round-trip -> no spill), 4x4 f32x4 acc per
// wave, BK=64. (b) ks_fused pass-2 strength reduction: fold 1/Z into the
// exp2 argument (5 VALU/element vs 7).
//
// Workspace (byte offsets):
//   xb      bf16[4096*768]      @ 0
//   qwb     bf16[2304*768]      @ 6291456
//   pwb     bf16[768*768]       @ 9830400
//   qb      bf16[48*1024*64]    @ 11010048
//   kb      bf16[48*1024*64]    @ 17301504
//   v       f32 [48*1024*64]    @ 23592960
//   ctxb    bf16[4096*768]      @ 36175872
//   lse     f32 [48*1024]       @ 42467328
//   mask    f32 [1024]          @ 42663936
//   keep    int [1]             @ 42668032
//   colSP   f32 [2048]          @ 42668544   (colS[1024] ++ colP[1024])
// total ~42.7 MB
// ---------------------------------------------------------------------------

typedef __bf16 bf16x8 __attribute__((ext_vector_type(8)));
typedef __bf16 bf16x4 __attribute__((ext_vector_type(4)));
typedef float  f32x4  __attribute__((ext_vector_type(4)));

#define MFMA16(a, b, c) __builtin_amdgcn_mfma_f32_16x16x32_bf16((a), (b), (c), 0, 0, 0)
#define LOG2E_8 0.18033688f  /* 0.125 * log2(e) */

__device__ __forceinline__ void ld_glds16(const __bf16* g, __bf16* s) {
  __builtin_amdgcn_global_load_lds(
      (const __attribute__((address_space(1))) unsigned int*)g,
      (__attribute__((address_space(3))) unsigned int*)s, 16, 0, 0);
}

// --- 1. fp32 -> bf16 conversion + zero colSP/keepCnt -----------------------
__global__ __launch_bounds__(256) void kc_conv(
    const float* __restrict__ x, const float* __restrict__ qw, const float* __restrict__ pw,
    __bf16* __restrict__ xb, __bf16* __restrict__ qwb, __bf16* __restrict__ pwb,
    float* __restrict__ colSP, int* __restrict__ keepCnt)
{
  const int i = blockIdx.x * 256 + threadIdx.x;
  const float4* src;
  __bf16* dst;
  int j;
  if (i < 786432)       { src = (const float4*)x;  dst = xb;  j = i; }
  else if (i < 1228800) { src = (const float4*)qw; dst = qwb; j = i - 786432; }
  else                  { src = (const float4*)pw; dst = pwb; j = i - 1228800; }
  const float4 f = src[j];
  bf16x4 o;
  o[0] = (__bf16)f.x; o[1] = (__bf16)f.y; o[2] = (__bf16)f.z; o[3] = (__bf16)f.w;
  *(bf16x4*)(dst + 4 * (size_t)j) = o;
  if (i < 2048) colSP[i] = 0.f;
  if (i == 0) *keepCnt = 0;
}

// --- 2. QKV GEMM, m97-style: 128x128 tile, async global->LDS staging -------
// grid (18, 32): c0 = bx*128 (N=2304), r0 = by*128 (M=4096). Wave (wm,wn)
// owns a 64x64 patch (4x4 of 16x16). BK=64; 8 global_load_lds(16B)/wave/stage.
__global__ __launch_bounds__(256) void kg_qkv(
    const __bf16* __restrict__ A, const __bf16* __restrict__ Bm,
    __bf16* __restrict__ qb, __bf16* __restrict__ kb, float* __restrict__ v)
{
  __shared__ __bf16 As[128 * 64];
  __shared__ __bf16 Bs[128 * 64];
  const int tid = threadIdx.x;
  const int w = tid >> 6, lane = tid & 63, quad = lane >> 4, l = lane & 15;
  const int wm = w >> 1, wn = w & 1;
  const int r0 = blockIdx.y * 128, c0 = blockIdx.x * 128;
  // staging geometry: instruction si covers tile rows 8*si..8*si+7 (1KB);
  // lane covers row 8*si + lane/8, cols (lane%8)*8..+8.
  const int srow = lane >> 3, skk = (lane & 7) * 8;

  f32x4 acc[4][4] = {};

  for (int k0 = 0; k0 < 768; k0 += 64) {
    if (k0) __syncthreads();  // previous compute done -> LDS writable
#pragma unroll
    for (int s = 0; s < 4; ++s) {
      const int si = w * 4 + s;               // 0..15
      const int row = si * 8 + srow;
      ld_glds16(A + (size_t)(r0 + row) * 768 + k0 + skk, &As[si * 512]);
      ld_glds16(Bm + (size_t)(c0 + row) * 768 + k0 + skk, &Bs[si * 512]);
    }
    __syncthreads();  // drains vmcnt -> staged tiles visible
#pragma unroll
    for (int kk = 0; kk < 2; ++kk) {
      bf16x8 af[4], bf[4];
#pragma unroll
      for (int t = 0; t < 4; ++t) {
        af[t] = *(const bf16x8*)&As[(wm * 64 + t * 16 + l) * 64 + kk * 32 + quad * 8];
        bf[t] = *(const bf16x8*)&Bs[(wn * 64 + t * 16 + l) * 64 + kk * 32 + quad * 8];
      }
#pragma unroll
      for (int mt = 0; mt < 4; ++mt)
#pragma unroll
        for (int nt = 0; nt < 4; ++nt)
          acc[mt][nt] = MFMA16(af[mt], bf[nt], acc[mt][nt]);
    }
  }

  // scatter epilogue: part uniform per block (c0 128-aligned, 768%128==0 -> no,
  // 768/128=6 so block cols never straddle a part boundary)
  const int part = c0 / 768;
  const int cbase = c0 % 768;
#pragma unroll
  for (int mt = 0; mt < 4; ++mt) {
#pragma unroll
    for (int nt = 0; nt < 4; ++nt) {
      const int cc = cbase + wn * 64 + nt * 16 + l;  // 0..767
      const int h = cc >> 6, d = cc & 63;
#pragma unroll
      for (int i = 0; i < 4; ++i) {
        const int rg = r0 + wm * 64 + mt * 16 + quad * 4 + i;
        const int b_ = rg >> 10, n = rg & 1023;
        const size_t off = ((size_t)(b_ * 12 + h) * 1024 + n) * 64 + d;
        const float val = acc[mt][nt][i];
        if (part == 0)      qb[off] = (__bf16)val;
        else if (part == 1) kb[off] = (__bf16)val;
        else                v[off]  = val;
      }
    }
  }
}

// --- 3. fused stats v2 (r10 winner + pass-2 strength reduction) ------------
// grid (48, 16): block = (bh, 64 rows) x 1024 cols. Wave w owns column-tile
// ct=w; all 4 Q row-tiles resident. Double-buffered Ks, one barrier/stage.
__global__ __launch_bounds__(256) void ks_fused(
    const __bf16* __restrict__ qb, const __bf16* __restrict__ kb,
    float* __restrict__ lse, float* __restrict__ colSP)
{
  __shared__ __bf16 Ks[2][64 * 72];
  __shared__ float sS[1024];
  __shared__ float sP[1024];
  __shared__ float zrow[64];
  const int tid = threadIdx.x;
  const int w = tid >> 6, lane = tid & 63, quad = lane >> 4, l = lane & 15;
  const int bh = blockIdx.x, r0 = blockIdx.y * 64;
  const int row = tid >> 3, ko = (tid & 7) * 8;
  for (int i = tid; i < 1024; i += 256) { sS[i] = 0.f; sP[i] = 0.f; }
  if (tid < 64) zrow[tid] = 0.f;

  const __bf16* qbase = qb + ((size_t)bh * 1024 + r0 + l) * 64;
  bf16x8 aq0[4], aq1[4];
#pragma unroll
  for (int rt = 0; rt < 4; ++rt) {
    aq0[rt] = *(const bf16x8*)(qbase + rt * 1024 + quad * 8);
    aq1[rt] = *(const bf16x8*)(qbase + rt * 1024 + 32 + quad * 8);
  }
  const __bf16* kbase = kb + (size_t)bh * 65536;  // [1024][64]
  const f32x4 zero = {0.f, 0.f, 0.f, 0.f};
  const int koff = (w * 16 + l) * 72 + quad * 8;

  uint4 ka0 = *(const uint4*)(kbase + (size_t)row * 64 + ko);
  uint4 ka1 = *(const uint4*)(kbase + (size_t)(row + 32) * 64 + ko);

  float z[16] = {};
  // ---- pass 1: row sums of exp ----
  for (int s = 0; s < 16; ++s) {
    __bf16* Kw = Ks[s & 1];
    *(uint4*)&Kw[row * 72 + ko] = ka0;
    *(uint4*)&Kw[(row + 32) * 72 + ko] = ka1;
    __syncthreads();  // chunk s visible; no vmem in flight here
    const int nxt = (s + 1) & 15;  // s==15 prefetches chunk 0 for pass 2
    ka0 = *(const uint4*)(kbase + (size_t)(nxt * 64 + row) * 64 + ko);
    ka1 = *(const uint4*)(kbase + (size_t)(nxt * 64 + row + 32) * 64 + ko);
    const bf16x8 kf0 = *(const bf16x8*)&Kw[koff];
    const bf16x8 kf1 = *(const bf16x8*)&Kw[koff + 32];
#pragma unroll
    for (int rt = 0; rt < 4; ++rt) {
      f32x4 acc = MFMA16(aq0[rt], kf0, zero);
      acc = MFMA16(aq1[rt], kf1, acc);
#pragma unroll
      for (int r = 0; r < 4; ++r) z[rt * 4 + r] += exp2f(acc[r] * LOG2E_8);
    }
  }
#pragma unroll
  for (int off = 1; off < 16; off <<= 1) {
#pragma unroll
    for (int i = 0; i < 16; ++i) z[i] += __shfl_xor(z[i], off);
  }
  if (l == 0) {
#pragma unroll
    for (int rt = 0; rt < 4; ++rt)
#pragma unroll
      for (int r = 0; r < 4; ++r)
        atomicAdd(&zrow[rt * 16 + quad * 4 + r], z[rt * 4 + r]);
  }
  __syncthreads();  // zrow complete
  if (tid < 64) lse[bh * 1024 + r0 + tid] = __logf(zrow[tid]);
  float nlb[16], nlg[16];  // -log2(Z), -ln(Z)
#pragma unroll
  for (int rt = 0; rt < 4; ++rt) {
#pragma unroll
    for (int r = 0; r < 4; ++r) {
      const float Z = zrow[rt * 16 + quad * 4 + r];
      const float lg = __logf(Z);
      nlg[rt * 4 + r] = -lg;
      nlb[rt * 4 + r] = -lg * 1.44269504f;
    }
  }

  // ---- pass 2: column sums of p and p*logp ----
  // p = exp2(fma(a, c, -log2 Z)); logp = fma(a, 0.125, -ln Z); 5 VALU/element.
  for (int s = 0; s < 16; ++s) {
    __bf16* Kw = Ks[s & 1];
    *(uint4*)&Kw[row * 72 + ko] = ka0;
    *(uint4*)&Kw[(row + 32) * 72 + ko] = ka1;
    __syncthreads();
    if (s < 15) {
      ka0 = *(const uint4*)(kbase + (size_t)((s + 1) * 64 + row) * 64 + ko);
      ka1 = *(const uint4*)(kbase + (size_t)((s + 1) * 64 + row + 32) * 64 + ko);
    }
    const bf16x8 kf0 = *(const bf16x8*)&Kw[koff];
    const bf16x8 kf1 = *(const bf16x8*)&Kw[koff + 32];
    float cs = 0.f, cp = 0.f;
#pragma unroll
    for (int rt = 0; rt < 4; ++rt) {
      f32x4 acc = MFMA16(aq0[rt], kf0, zero);
      acc = MFMA16(aq1[rt], kf1, acc);
#pragma unroll
      for (int r = 0; r < 4; ++r) {
        const float a = acc[r];
        const float t = exp2f(fmaf(a, LOG2E_8, nlb[rt * 4 + r]));
        const float d = fmaf(a, 0.125f, nlg[rt * 4 + r]);
        cs += t;
        cp = fmaf(t, d, cp);
      }
    }
    cs += __shfl_xor(cs, 16); cs += __shfl_xor(cs, 32);
    cp += __shfl_xor(cp, 16); cp += __shfl_xor(cp, 32);
    if (lane < 16) {  // wave-private columns: plain LDS accumulate
      sS[s * 64 + w * 16 + l] += cs;
      sP[s * 64 + w * 16 + l] += cp;
    }
  }
  __syncthreads();
  for (int i = tid; i < 1024; i += 256) {
    atomicAdd(&colSP[i], sS[i]);
    atomicAdd(&colSP[1024 + i], sP[i]);
  }
}

// --- 4. entropy -> mask + keepCnt ------------------------------------------
__global__ void k_mask(const float* __restrict__ colSP, const int* __restrict__ cur_epoch,
                       float* __restrict__ mask, int* __restrict__ keepCnt)
{
  const int j = threadIdx.x;
  const float s = colSP[j];
  const float ent = __logf(s) - colSP[1024 + j] / s;
  const int ce = cur_epoch[0];
  float factor = 0.f;
  for (int i = 1; i <= ce; ++i) factor += __expf(-(float)i);
  factor *= 5.0f;
  const float thr = __logf(768.0f) - factor;
  const int keep = (ent <= thr) ? 1 : 0;
  mask[j] = keep ? 1.0f : 0.0f;
  if (keep) atomicAdd(keepCnt, 1);
}

// --- 5. masked AV -> ctxb (bf16). No-op when no column survives. -----------
__global__ __launch_bounds__(256) void k_av(
    const __bf16* __restrict__ qb, const __bf16* __restrict__ kb,
    const float* __restrict__ v, const float* __restrict__ lse,
    const float* __restrict__ mask, const int* __restrict__ keepCnt,
    __bf16* __restrict__ ctxb)
{
  if (*keepCnt == 0) return;  // ctxb unused downstream in this case
  const int tid = threadIdx.x;
  const int bh = blockIdx.x, r0 = blockIdx.y * 32;
  const int b_ = bh / 12, h = bh % 12;
  __shared__ float qs[32][64];
  __shared__ float pbuf[4][8][64];
  for (int i = tid; i < 2048; i += 256)
    qs[i >> 6][i & 63] = (float)qb[((size_t)bh * 1024 + r0) * 64 + i];
  __syncthreads();
  const int w = tid >> 6, l = tid & 63, rb = w * 8;
  float ls[8];
#pragma unroll
  for (int i = 0; i < 8; ++i) ls[i] = lse[bh * 1024 + r0 + rb + i];
  float acc[8] = {};
  for (int chunk = 0; chunk < 16; ++chunk) {
    const float mk = mask[chunk * 64 + l];
    if (__ballot(mk != 0.0f) == 0ull) continue;  // block-uniform
    const __bf16* kp = kb + ((size_t)bh * 1024 + chunk * 64 + l) * 64;
    float s[8] = {};
    for (int d0 = 0; d0 < 64; d0 += 8) {
      const bf16x8 kf = *(const bf16x8*)(kp + d0);
#pragma unroll
      for (int dd = 0; dd < 8; ++dd) {
        const float kv = (float)kf[dd];
#pragma unroll
        for (int i = 0; i < 8; ++i) s[i] += qs[rb + i][d0 + dd] * kv;
      }
    }
    __syncthreads();
#pragma unroll
    for (int i = 0; i < 8; ++i)
      pbuf[w][i][l] = __expf(s[i] * 0.125f - ls[i]) * mk;
    __syncthreads();
    const float* vp = v + ((size_t)bh * 1024 + chunk * 64) * 64 + l;
    for (int jj = 0; jj < 64; ++jj) {
      const float vv = vp[(size_t)jj * 64];
#pragma unroll
      for (int i = 0; i < 8; ++i) acc[i] += pbuf[w][i][jj] * vv;
    }
  }
#pragma unroll
  for (int i = 0; i < 8; ++i)
    ctxb[((size_t)(b_ * 1024 + r0 + rb + i)) * 768 + h * 64 + l] = (__bf16)acc[i];
}

// --- 6. proj GEMM: out = ctxb @ pwb.T + bias; bias-only when keep==0 -------
__global__ __launch_bounds__(256) void kg_proj(
    const __bf16* __restrict__ A, const __bf16* __restrict__ Bm,
    const float* __restrict__ bias, const int* __restrict__ keepCnt,
    float* __restrict__ out)
{
  const int tid = threadIdx.x;
  const int w = tid >> 6, lane = tid & 63, quad = lane >> 4, l = lane & 15;
  const int r0 = blockIdx.y * 64, c0 = blockIdx.x * 64;
  if (*keepCnt == 0) {  // ctx == 0 -> out = bias (uniform branch)
#pragma unroll
    for (int ct = 0; ct < 4; ++ct) {
      const int c = c0 + ct * 16 + l;
      const float bv = bias[c];
#pragma unroll
      for (int i = 0; i < 4; ++i) {
        const int rg = r0 + w * 16 + quad * 4 + i;
        out[(size_t)rg * 768 + c] = bv;
      }
    }
    return;
  }
  __shared__ __bf16 As[64 * 72];
  __shared__ __bf16 Bs[64 * 72];
  const int row = tid >> 3, ko = (tid & 7) * 8;
  const f32x4 zero = {0.f, 0.f, 0.f, 0.f};
  f32x4 acc[4];
#pragma unroll
  for (int ct = 0; ct < 4; ++ct) acc[ct] = zero;

  uint4 a0 = *(const uint4*)(A + (size_t)(r0 + row) * 768 + ko);
  uint4 a1 = *(const uint4*)(A + (size_t)(r0 + row + 32) * 768 + ko);
  uint4 b0 = *(const uint4*)(Bm + (size_t)(c0 + row) * 768 + ko);
  uint4 b1 = *(const uint4*)(Bm + (size_t)(c0 + row + 32) * 768 + ko);

  for (int k0 = 0; k0 < 768; k0 += 64) {
    __syncthreads();
    *(uint4*)&As[row * 72 + ko] = a0;
    *(uint4*)&As[(row + 32) * 72 + ko] = a1;
    *(uint4*)&Bs[row * 72 + ko] = b0;
    *(uint4*)&Bs[(row + 32) * 72 + ko] = b1;
    __syncthreads();
    if (k0 < 704) {
      a0 = *(const uint4*)(A + (size_t)(r0 + row) * 768 + k0 + 64 + ko);
      a1 = *(const uint4*)(A + (size_t)(r0 + row + 32) * 768 + k0 + 64 + ko);
      b0 = *(const uint4*)(Bm + (size_t)(c0 + row) * 768 + k0 + 64 + ko);
      b1 = *(const uint4*)(Bm + (size_t)(c0 + row + 32) * 768 + k0 + 64 + ko);
    }
    const bf16x8 af0 = *(const bf16x8*)&As[(w * 16 + l) * 72 + quad * 8];
    const bf16x8 af1 = *(const bf16x8*)&As[(w * 16 + l) * 72 + 32 + quad * 8];
#pragma unroll
    for (int ct = 0; ct < 4; ++ct) {
      const bf16x8 bf0 = *(const bf16x8*)&Bs[(ct * 16 + l) * 72 + quad * 8];
      const bf16x8 bf1 = *(const bf16x8*)&Bs[(ct * 16 + l) * 72 + 32 + quad * 8];
      acc[ct] = MFMA16(af0, bf0, acc[ct]);
      acc[ct] = MFMA16(af1, bf1, acc[ct]);
    }
  }
#pragma unroll
  for (int ct = 0; ct < 4; ++ct) {
    const int c = c0 + ct * 16 + l;
#pragma unroll
    for (int i = 0; i < 4; ++i) {
      const int rg = r0 + w * 16 + quad * 4 + i;
      out[(size_t)rg * 768 + c] = acc[ct][i] + bias[c];
    }
  }
}

extern "C" void kernel_launch(void* const* d_in, const int* in_sizes, int n_in,
                              void* d_out, int out_size, void* d_ws, size_t ws_size,
                              hipStream_t stream)
{
  const float* x      = (const float*)d_in[0];
  const float* qkv_w  = (const float*)d_in[1];
  const float* proj_w = (const float*)d_in[2];
  const float* proj_b = (const float*)d_in[3];
  const int*   cur_ep = (const int*)d_in[4];

  char* W = (char*)d_ws;
  __bf16* xb    = (__bf16*)(W + 0);
  __bf16* qwb   = (__bf16*)(W + 6291456);
  __bf16* pwb   = (__bf16*)(W + 9830400);
  __bf16* qb    = (__bf16*)(W + 11010048);
  __bf16* kb    = (__bf16*)(W + 17301504);
  float*  v     = (float*) (W + 23592960);
  __bf16* ctxb  = (__bf16*)(W + 36175872);
  float*  lse   = (float*) (W + 42467328);
  float*  mask  = (float*) (W + 42663936);
  int*    keep  = (int*)   (W + 42668032);
  float*  colSP = (float*) (W + 42668544);
  float*  out   = (float*)d_out;

  kc_conv<<<5376, 256, 0, stream>>>(x, qkv_w, proj_w, xb, qwb, pwb, colSP, keep);
  kg_qkv<<<dim3(18, 32), 256, 0, stream>>>(xb, qwb, qb, kb, v);
  ks_fused<<<dim3(48, 16), 256, 0, stream>>>(qb, kb, lse, colSP);
  k_mask<<<1, 1024, 0, stream>>>(colSP, cur_ep, mask, keep);
  k_av<<<dim3(48, 32), 256, 0, stream>>>(qb, kb, v, lse, mask, keep, ctxb);
  kg_proj<<<dim3(12, 64), 256, 0, stream>>>(ctxb, pwb, proj_b, keep, out);
}